// Round 6
// baseline (504.877 us; speedup 1.0000x reference)
//
#include <hip/hip_runtime.h>
#include <cstdint>
#include <cstddef>

typedef unsigned short u16;
typedef __attribute__((ext_vector_type(4))) float f32x4;
typedef __attribute__((ext_vector_type(8))) short s16x8;

#define D_EMB 1024
#define NSEQ 1024
#define NB 8
#define NH 16
#define HS 64
#define DFF 4096
#define MTOT (NB*NSEQ)

__device__ __forceinline__ u16 f2bf(float f){
  unsigned u = __float_as_uint(f);
  u += 0x7FFFu + ((u >> 16) & 1u);     // round-to-nearest-even
  return (u16)(u >> 16);
}

__device__ __forceinline__ void gload_lds16(const void* g, void* l){
  __builtin_amdgcn_global_load_lds((const __attribute__((address_space(1))) void*)g,
                                   (__attribute__((address_space(3))) void*)l, 16, 0, 0);
}

#define WAITV(n) asm volatile("s_waitcnt vmcnt(" #n ")" ::: "memory")

// ---------------- tiled transpose + fp32->bf16 convert ----------------
__global__ void transpose_cvt(const float* __restrict__ in, u16* __restrict__ out,
                              int R, int C, size_t inStride, size_t outStride){
  __shared__ float t[32][33];
  const float* ip = in + (size_t)blockIdx.z * inStride;
  u16* op = out + (size_t)blockIdx.z * outStride;
  int c0 = blockIdx.x * 32, r0 = blockIdx.y * 32;
  int tx = threadIdx.x, ty = threadIdx.y;
#pragma unroll
  for (int j = 0; j < 32; j += 8)
    t[ty + j][tx] = ip[(size_t)(r0 + ty + j) * C + (c0 + tx)];
  __syncthreads();
#pragma unroll
  for (int j = 0; j < 32; j += 8)
    op[(size_t)(c0 + ty + j) * R + (r0 + tx)] = f2bf(t[tx][ty + j]);
}

// ---------------- LayerNorm (fp32 in, bf16 out) ----------------
__global__ __launch_bounds__(256) void ln_kernel(const float* __restrict__ x,
    const float* __restrict__ g, const float* __restrict__ bb, u16* __restrict__ out){
  int row = blockIdx.x;
  const float* xr = x + (size_t)row * D_EMB;
  int c = threadIdx.x * 4;
  f32x4 v = *(const f32x4*)(xr + c);
  float s1 = v[0] + v[1] + v[2] + v[3];
  float s2 = v[0]*v[0] + v[1]*v[1] + v[2]*v[2] + v[3]*v[3];
#pragma unroll
  for (int m = 32; m > 0; m >>= 1){ s1 += __shfl_xor(s1, m); s2 += __shfl_xor(s2, m); }
  __shared__ float ps1[4], ps2[4];
  int w = threadIdx.x >> 6;
  if ((threadIdx.x & 63) == 0){ ps1[w] = s1; ps2[w] = s2; }
  __syncthreads();
  s1 = ps1[0] + ps1[1] + ps1[2] + ps1[3];
  s2 = ps2[0] + ps2[1] + ps2[2] + ps2[3];
  float mu = s1 * (1.f / D_EMB);
  float var = s2 * (1.f / D_EMB) - mu * mu;
  float rs = rsqrtf(var + 1e-5f);
  ushort4 o;
  o.x = f2bf((v[0]-mu)*rs*g[c+0] + bb[c+0]);
  o.y = f2bf((v[1]-mu)*rs*g[c+1] + bb[c+1]);
  o.z = f2bf((v[2]-mu)*rs*g[c+2] + bb[c+2]);
  o.w = f2bf((v[3]-mu)*rs*g[c+3] + bb[c+3]);
  *(ushort4*)(out + (size_t)row * D_EMB + c) = o;
}

// ============ 256-row phased GEMM, BK=32, 4-deep prefetch ring ============
// C = A[M,K] * Bt[N,K]^T. 512 thr = 8 waves. Per K-tile: 2 phases x 16(8) MFMA.
// Ring: buf = kt&3; tile kt stages tile kt+3 (A in phase0, B in phase1).
// One counted vmcnt per tile: steady vmcnt(2*PL) certifies tile kt+1; tail
// peeled explicitly (vmcnt(PL), vmcnt(0), none) — ledger holds every tile.
// BK=32 rows are 64B: the 4 lg-lanes of each row read all 4 chunks -> reads
// are bank-balanced with a LINEAR layout; no swizzle needed anywhere.
template<int MODE, int BNT>
__global__ __launch_bounds__(512) void gemm256(
    const u16* __restrict__ A, const u16* __restrict__ Bt,
    int M, int N, int K,
    const float* __restrict__ bias0, const float* __restrict__ bias1,
    const float* __restrict__ bias2, const float* __restrict__ resid,
    void* __restrict__ o0, void* __restrict__ o1, void* __restrict__ o2)
{
  constexpr int BMT = 256;
  constexpr int WCN = BNT/64, WRN = 8/WCN;       // wave grid (cols, rows)
  constexpr int WROWS = BMT/WRN;                 // rows per wave (128 or 64)
  constexpr int RF = WROWS/16, RH = RF/2;        // row frags / per phase
  constexpr int ALD = 2;                         // A 16KB / (512*16B)
  constexpr int BLD = (BNT*32*2)/(512*16);       // 2 (BNT=256) or 1 (BNT=128)
  constexpr int PL  = ALD + BLD;                 // loads per tile
  constexpr int ABUF = BMT*32, BBUF = BNT*32;    // u16 per ring buffer
  extern __shared__ u16 lds[];
  u16* const Ab = lds;                           // [4][ABUF]
  u16* const Bb = lds + 4*ABUF;                  // [4][BBUF]

  const int tid = threadIdx.x;
  const int wid = tid>>6, lane = tid&63, lr = lane&15, lg = lane>>4;
  const int wr = wid/WCN, wc = wid%WCN;

  // XCD swizzle (nwg divisible by 8 for all our grids)
  const int gx = gridDim.x;
  const int nwg = gx * gridDim.y;
  const int bid = blockIdx.x + blockIdx.y*gx;
  const int wg = (bid&7)*(nwg>>3) + (bid>>3);
  const int m0 = (wg % gx) * BMT;
  const int n0 = (wg / gx) * BNT;

  const int nkt = K/32;
  const int srow = tid>>2, sc8 = (tid&3)*8;      // staging row / chunk

  auto stageA = [&](int kt3){
    const u16* src = A + (size_t)(m0 + srow)*K + kt3*32 + sc8;
    u16* dst = Ab + (kt3&3)*ABUF + tid*8;
    gload_lds16(src, dst);
    gload_lds16(src + (size_t)128*K, dst + 4096);
  };
  auto stageB = [&](int kt3){
    const u16* src = Bt + (size_t)(n0 + srow)*K + kt3*32 + sc8;
    u16* dst = Bb + (kt3&3)*BBUF + tid*8;
    gload_lds16(src, dst);
    if constexpr (BLD == 2) gload_lds16(src + (size_t)128*K, dst + 4096);
  };
  auto rdA = [&](int kt, int fm) -> s16x8 {
    const int row = wr*WROWS + fm*16 + lr;
    return *(const s16x8*)&Ab[(kt&3)*ABUF + row*32 + lg*8];
  };
  auto rdB = [&](int kt, int fn) -> s16x8 {
    const int row = wc*64 + fn*16 + lr;
    return *(const s16x8*)&Bb[(kt&3)*BBUF + row*32 + lg*8];
  };

  f32x4 acc[RF][4];
#pragma unroll
  for (int i = 0; i < RF; i++)
#pragma unroll
    for (int j = 0; j < 4; j++) acc[i][j] = {0.f,0.f,0.f,0.f};

  // tile body. wsel: 2 = steady (drain to 2*PL), 1 = drain to PL,
  // 0 = drain to 0, -1 = last tile (no wait, no trailing barrier).
  auto tile = [&](int kt, bool doStage, int wsel){
    s16x8 af[RH], bf[4];
    // ---- phase 0: A-low frags + all B frags ----
#pragma unroll
    for (int j = 0; j < RH; ++j) af[j] = rdA(kt, j);
#pragma unroll
    for (int f = 0; f < 4;  ++f) bf[f] = rdB(kt, f);
    if (doStage) stageA(kt+3);
    __builtin_amdgcn_s_barrier();
    asm volatile("s_waitcnt lgkmcnt(0)" ::: "memory");
    __builtin_amdgcn_sched_barrier(0);
    __builtin_amdgcn_s_setprio(1);
#pragma unroll
    for (int j = 0; j < RH; ++j)
#pragma unroll
      for (int f = 0; f < 4; ++f)
        acc[j][f] = __builtin_amdgcn_mfma_f32_16x16x32_bf16(af[j], bf[f], acc[j][f], 0, 0, 0);
    __builtin_amdgcn_s_setprio(0);
    __builtin_amdgcn_s_barrier();
    // ---- phase 1: A-high frags, reuse bf ----
#pragma unroll
    for (int j = 0; j < RH; ++j) af[j] = rdA(kt, RH + j);
    if (doStage) stageB(kt+3);
    __builtin_amdgcn_s_barrier();
    asm volatile("s_waitcnt lgkmcnt(0)" ::: "memory");
    __builtin_amdgcn_sched_barrier(0);
    __builtin_amdgcn_s_setprio(1);
#pragma unroll
    for (int j = 0; j < RH; ++j)
#pragma unroll
      for (int f = 0; f < 4; ++f)
        acc[RH+j][f] = __builtin_amdgcn_mfma_f32_16x16x32_bf16(af[j], bf[f], acc[RH+j][f], 0, 0, 0);
    __builtin_amdgcn_s_setprio(0);
    if (wsel == 2){
      if constexpr (PL == 4) WAITV(8); else WAITV(6);
      __builtin_amdgcn_s_barrier();
    } else if (wsel == 1){
      if constexpr (PL == 4) WAITV(4); else WAITV(3);
      __builtin_amdgcn_s_barrier();
    } else if (wsel == 0){
      WAITV(0);
      __builtin_amdgcn_s_barrier();
    }
  };

  // prologue: stage tiles 0,1,2; certify tile 0 (drain to 2*PL)
  stageA(0 - 3 + 3); stageB(0);   // kt3 = 0
  stageA(1); stageB(1);
  stageA(2); stageB(2);
  if constexpr (PL == 4) WAITV(8); else WAITV(6);
  __builtin_amdgcn_s_barrier();

  for (int kt = 0; kt < nkt - 3; ++kt) tile(kt, true, 2);
  tile(nkt-3, false, 1);
  tile(nkt-2, false, 0);
  tile(nkt-1, false, -1);

  // epilogue
#pragma unroll
  for (int fm = 0; fm < RF; fm++){
    const int gmb = m0 + wr*WROWS + fm*16 + lg*4;
#pragma unroll
    for (int fn = 0; fn < 4; fn++){
      const int gn = n0 + wc*64 + fn*16 + lr;
#pragma unroll
      for (int i = 0; i < 4; i++){
        const int gm = gmb + i;
        float v = acc[fm][fn][i];
        if (MODE == 0){
          const int cls = gn >> 10, nn = gn & 1023;
          if (cls == 0)      ((u16*)o0)[(size_t)gm * D_EMB + nn] = f2bf(v + bias0[nn]);
          else if (cls == 1) ((u16*)o1)[(size_t)gm * D_EMB + nn] = f2bf(v + bias1[nn]);
          else {
            const int hh = nn >> 6, ss = nn & 63, bb = gm >> 10, tt = gm & 1023;
            ((u16*)o2)[(((size_t)(bb * NH + hh)) * HS + ss) * NSEQ + tt] = f2bf(v + bias2[nn]);
          }
        } else if (MODE == 1){
          ((float*)o0)[(size_t)gm * N + gn] = resid[(size_t)gm * N + gn] + v + bias0[gn];
        } else {
          float y = v + bias0[gn];
          y = y > 0.f ? y : 0.01f * y;
          ((u16*)o0)[(size_t)gm * N + gn] = f2bf(y);
        }
      }
    }
  }
}

// ---------------- fallback GEMM (proven round-3 128x128) ----------------
#define BM 128
#define BN 128
#define BK 32
template<int MODE>
__global__ __launch_bounds__(256) void gemm_bt(
    const u16* __restrict__ A, const u16* __restrict__ Bt,
    int M, int N, int K,
    const float* __restrict__ bias0, const float* __restrict__ bias1,
    const float* __restrict__ bias2, const float* __restrict__ resid,
    void* __restrict__ o0, void* __restrict__ o1, void* __restrict__ o2)
{
  __shared__ alignas(16) u16 Al[2][BM*BK];
  __shared__ alignas(16) u16 Bl[2][BN*BK];
  const int tid = threadIdx.x;
  const int m0 = blockIdx.x * BM, n0 = blockIdx.y * BN;
  const int wid = tid >> 6, lane = tid & 63;
  const int wm = (wid >> 1) * 64, wn = (wid & 1) * 64;
  const int lr = lane & 15, lg = lane >> 4;

  f32x4 acc[4][4];
#pragma unroll
  for (int i = 0; i < 4; i++)
#pragma unroll
    for (int j = 0; j < 4; j++) acc[i][j] = {0.f,0.f,0.f,0.f};

  const int nk = K / BK;
  const int arow = tid >> 2, akg = tid & 3;

  auto stage = [&](int bufi, int kt){
    const int k0 = kt * BK;
    const u16* ap = A  + (size_t)(m0 + arow) * K + k0 + akg * 8;
    gload_lds16(ap,                  &Al[bufi][tid * 8]);
    gload_lds16(ap + (size_t)64 * K, &Al[bufi][2048 + tid * 8]);
    const u16* bp = Bt + (size_t)(n0 + arow) * K + k0 + akg * 8;
    gload_lds16(bp,                  &Bl[bufi][tid * 8]);
    gload_lds16(bp + (size_t)64 * K, &Bl[bufi][2048 + tid * 8]);
  };

  stage(0, 0);
  for (int kt = 0; kt < nk; ++kt){
    __syncthreads();
    if (kt + 1 < nk) stage((kt + 1) & 1, kt + 1);
    const int bufi = kt & 1;
    s16x8 af[4], bfr[4];
#pragma unroll
    for (int i = 0; i < 4; i++){
      af[i]  = *(const s16x8*)&Al[bufi][(wm + i*16 + lr) * BK + lg * 8];
      bfr[i] = *(const s16x8*)&Bl[bufi][(wn + i*16 + lr) * BK + lg * 8];
    }
#pragma unroll
    for (int i = 0; i < 4; i++)
#pragma unroll
      for (int j = 0; j < 4; j++)
        acc[i][j] = __builtin_amdgcn_mfma_f32_16x16x32_bf16(af[i], bfr[j], acc[i][j], 0, 0, 0);
  }

#pragma unroll
  for (int fm = 0; fm < 4; fm++){
    const int gmb = m0 + wm + fm * 16 + lg * 4;
#pragma unroll
    for (int fn = 0; fn < 4; fn++){
      const int gn = n0 + wn + fn * 16 + lr;
#pragma unroll
      for (int i = 0; i < 4; i++){
        const int gm = gmb + i;
        float v = acc[fm][fn][i];
        if (MODE == 0){
          const int cls = gn >> 10, nn = gn & 1023;
          if (cls == 0)      ((u16*)o0)[(size_t)gm * D_EMB + nn] = f2bf(v + bias0[nn]);
          else if (cls == 1) ((u16*)o1)[(size_t)gm * D_EMB + nn] = f2bf(v + bias1[nn]);
          else {
            const int hh = nn >> 6, ss = nn & 63, bb = gm >> 10, tt = gm & 1023;
            ((u16*)o2)[(((size_t)(bb * NH + hh)) * HS + ss) * NSEQ + tt] = f2bf(v + bias2[nn]);
          }
        } else if (MODE == 1){
          ((float*)o0)[(size_t)gm * N + gn] = resid[(size_t)gm * N + gn] + v + bias0[gn];
        } else {
          float y = v + bias0[gn];
          y = y > 0.f ? y : 0.01f * y;
          ((u16*)o0)[(size_t)gm * N + gn] = f2bf(y);
        }
      }
    }
  }
}

// ---------------- flash attention (round-3, unchanged) ----------------
__global__ __launch_bounds__(256) void attn_kernel(
    const u16* __restrict__ Qb, const u16* __restrict__ Kb, const u16* __restrict__ VT,
    u16* __restrict__ attnC)
{
  const int bid = blockIdx.x;
  const int bh = bid & 127, qt = bid >> 7;
  const int b = bh >> 4, h = bh & 15;
  const int tid = threadIdx.x, w = tid >> 6, lane = tid & 63;
  const int lr = lane & 15, lg = lane >> 4;
  const int q0 = qt * 128 + w * 32;

  __shared__ alignas(16) u16 Kl[2][64*64];
  __shared__ alignas(16) u16 Vl[2][64*64];
  __shared__ alignas(16) u16 Pl[4][32][72];

  const int srow = tid >> 3, scg = tid & 7;
  const u16* kbase = Kb + (size_t)(b * NSEQ) * D_EMB + h * HS;
  const u16* vbase = VT + ((size_t)(b * NH + h)) * HS * NSEQ;

  auto stage = [&](int buf, int kt){
    const int tk = kt * 64;
#pragma unroll
    for (int p = 0; p < 2; ++p){
      const int row = srow + p * 32;
      const int sc = scg ^ (row & 7);
      gload_lds16(kbase + (size_t)(tk + row) * D_EMB + sc * 8, &Kl[buf][(p * 256 + tid) * 8]);
      gload_lds16(vbase + (size_t)row * NSEQ + tk + sc * 8,    &Vl[buf][(p * 256 + tid) * 8]);
    }
  };

  s16x8 aq[2][2];
#pragma unroll
  for (int rb = 0; rb < 2; rb++)
#pragma unroll
    for (int kh = 0; kh < 2; kh++)
      aq[rb][kh] = *(const s16x8*)(Qb + (size_t)(b * NSEQ + q0 + rb * 16 + lr) * D_EMB
                                   + h * HS + kh * 32 + lg * 8);

  float m_i[2][4], l_i[2][4];
  f32x4 zero = {0.f, 0.f, 0.f, 0.f};
  f32x4 ao[2][4];
#pragma unroll
  for (int rb = 0; rb < 2; rb++)
#pragma unroll
    for (int i = 0; i < 4; i++){ m_i[rb][i] = -1e30f; l_i[rb][i] = 0.f; ao[rb][i] = zero; }

  const float scale = 0.125f;
  const int rsw = lr & 7;

  stage(0, 0);
  for (int kt = 0; kt < NSEQ / 64; ++kt){
    __syncthreads();
    if (kt + 1 < NSEQ / 64) stage((kt + 1) & 1, kt + 1);
    const int cur = kt & 1;

    f32x4 sv[2][4];
#pragma unroll
    for (int rb = 0; rb < 2; rb++)
#pragma unroll
      for (int fn = 0; fn < 4; fn++) sv[rb][fn] = zero;
#pragma unroll
    for (int fn = 0; fn < 4; fn++){
      const int krow = fn * 16 + lr;
#pragma unroll
      for (int kh = 0; kh < 2; kh++){
        const int chunk = (kh * 4 + lg) ^ rsw;
        s16x8 kf = *(const s16x8*)&Kl[cur][krow * 64 + chunk * 8];
        sv[0][fn] = __builtin_amdgcn_mfma_f32_16x16x32_bf16(aq[0][kh], kf, sv[0][fn], 0, 0, 0);
        sv[1][fn] = __builtin_amdgcn_mfma_f32_16x16x32_bf16(aq[1][kh], kf, sv[1][fn], 0, 0, 0);
      }
    }

#pragma unroll
    for (int rb = 0; rb < 2; rb++){
      float p[4][4];
#pragma unroll
      for (int i = 0; i < 4; i++){
        float s0 = sv[rb][0][i] * scale, s1 = sv[rb][1][i] * scale;
        float s2 = sv[rb][2][i] * scale, s3 = sv[rb][3][i] * scale;
        float rmax = fmaxf(fmaxf(s0, s1), fmaxf(s2, s3));
#pragma unroll
        for (int mm = 8; mm > 0; mm >>= 1) rmax = fmaxf(rmax, __shfl_xor(rmax, mm));
        float mnew = fmaxf(m_i[rb][i], rmax);
        float fac = __expf(m_i[rb][i] - mnew);
        float p0 = __expf(s0 - mnew), p1 = __expf(s1 - mnew);
        float p2 = __expf(s2 - mnew), p3 = __expf(s3 - mnew);
        p[0][i] = p0; p[1][i] = p1; p[2][i] = p2; p[3][i] = p3;
        float rs = (p0 + p1) + (p2 + p3);
#pragma unroll
        for (int mm = 8; mm > 0; mm >>= 1) rs += __shfl_xor(rs, mm);
        l_i[rb][i] = l_i[rb][i] * fac + rs;
        m_i[rb][i] = mnew;
#pragma unroll
        for (int fn = 0; fn < 4; fn++) ao[rb][fn][i] *= fac;
      }
#pragma unroll
      for (int fn = 0; fn < 4; fn++)
#pragma unroll
        for (int i = 0; i < 4; i++)
          Pl[w][rb * 16 + lg * 4 + i][fn * 16 + lr] = f2bf(p[fn][i]);
    }

    s16x8 vf[4][2];
#pragma unroll
    for (int fn = 0; fn < 4; fn++){
      const int vrow = fn * 16 + lr;
#pragma unroll
      for (int kh = 0; kh < 2; kh++){
        const int chunk = (kh * 4 + lg) ^ rsw;
        vf[fn][kh] = *(const s16x8*)&Vl[cur][vrow * 64 + chunk * 8];
      }
    }
#pragma unroll
    for (int rb = 0; rb < 2; rb++){
      s16x8 pa0 = *(const s16x8*)&Pl[w][rb * 16 + lr][lg * 8];
      s16x8 pa1 = *(const s16x8*)&Pl[w][rb * 16 + lr][32 + lg * 8];
#pragma unroll
      for (int fn = 0; fn < 4; fn++){
        ao[rb][fn] = __builtin_amdgcn_mfma_f32_16x16x32_bf16(pa0, vf[fn][0], ao[rb][fn], 0, 0, 0);
        ao[rb][fn] = __builtin_amdgcn_mfma_f32_16x16x32_bf16(pa1, vf[fn][1], ao[rb][fn], 0, 0, 0);
      }
    }
  }

#pragma unroll
  for (int rb = 0; rb < 2; rb++)
#pragma unroll
    for (int fn = 0; fn < 4; fn++)
#pragma unroll
      for (int i = 0; i < 4; i++){
        float v = ao[rb][fn][i] / l_i[rb][i];
        attnC[(size_t)(b * NSEQ + q0 + rb * 16 + lg * 4 + i) * D_EMB + h * HS + fn * 16 + lr] = f2bf(v);
      }
}

// ---------------- host ----------------
extern "C" void kernel_launch(void* const* d_in, const int* in_sizes, int n_in,
                              void* d_out, int out_size, void* d_ws, size_t ws_size,
                              hipStream_t stream)
{
  const float* x    = (const float*)d_in[0];
  const float* Wq   = (const float*)d_in[1];
  const float* bq   = (const float*)d_in[2];
  const float* Wk   = (const float*)d_in[3];
  const float* bk   = (const float*)d_in[4];
  const float* Wv   = (const float*)d_in[5];
  const float* bv   = (const float*)d_in[6];
  const float* Wp   = (const float*)d_in[7];
  const float* bp   = (const float*)d_in[8];
  const float* W1   = (const float*)d_in[9];
  const float* b1   = (const float*)d_in[10];
  const float* W2   = (const float*)d_in[11];
  const float* b2   = (const float*)d_in[12];
  const float* ln1g = (const float*)d_in[13];
  const float* ln1b = (const float*)d_in[14];
  const float* ln2g = (const float*)d_in[15];
  const float* ln2b = (const float*)d_in[16];
  float* out = (float*)d_out;

  char* ws = (char*)d_ws;
  size_t off = 0;
  auto mk = [&](size_t bytes)->void*{ void* p = ws + off; off += (bytes + 255) & ~(size_t)255; return p; };
  u16*  h1    = (u16*) mk((size_t)MTOT * D_EMB * 2);
  u16*  Qb    = (u16*) mk((size_t)MTOT * D_EMB * 2);
  u16*  Kb    = (u16*) mk((size_t)MTOT * D_EMB * 2);
  u16*  VTb   = (u16*) mk((size_t)MTOT * D_EMB * 2);
  u16*  attnC = (u16*) mk((size_t)MTOT * D_EMB * 2);
  float* x1   = (float*)mk((size_t)MTOT * D_EMB * 4);
  u16*  h2    = (u16*) mk((size_t)MTOT * D_EMB * 2);
  u16*  ffb   = (u16*) mk((size_t)MTOT * DFF * 2);
  u16*  WqkvT = (u16*) mk((size_t)3 * D_EMB * D_EMB * 2);
  u16*  WpT   = (u16*) mk((size_t)D_EMB * D_EMB * 2);
  u16*  W1T   = (u16*) mk((size_t)D_EMB * DFF * 2);
  u16*  W2T   = (u16*) mk((size_t)D_EMB * DFF * 2);

  dim3 tb(32, 8, 1);
  transpose_cvt<<<dim3(HS/32, D_EMB/32, NH), tb, 0, stream>>>(Wq, WqkvT,                         D_EMB, HS, (size_t)D_EMB*HS, (size_t)HS*D_EMB);
  transpose_cvt<<<dim3(HS/32, D_EMB/32, NH), tb, 0, stream>>>(Wk, WqkvT + (size_t)D_EMB*D_EMB,   D_EMB, HS, (size_t)D_EMB*HS, (size_t)HS*D_EMB);
  transpose_cvt<<<dim3(HS/32, D_EMB/32, NH), tb, 0, stream>>>(Wv, WqkvT + (size_t)2*D_EMB*D_EMB, D_EMB, HS, (size_t)D_EMB*HS, (size_t)HS*D_EMB);
  transpose_cvt<<<dim3(D_EMB/32, D_EMB/32, 1), tb, 0, stream>>>(Wp, WpT,  D_EMB, D_EMB, 0, 0);
  transpose_cvt<<<dim3(DFF/32,  D_EMB/32, 1), tb, 0, stream>>>(W1, W1T,  D_EMB, DFF,   0, 0);
  transpose_cvt<<<dim3(D_EMB/32, DFF/32,  1), tb, 0, stream>>>(W2, W2T,  DFF,   D_EMB, 0, 0);

  ln_kernel<<<MTOT, 256, 0, stream>>>(x, ln1g, ln1b, h1);

  // opt-in to >64KB dynamic LDS; fall back to proven 128^2 GEMM on failure
  bool big = true;
  big &= hipFuncSetAttribute(reinterpret_cast<const void*>(&gemm256<0,256>),
                             hipFuncAttributeMaxDynamicSharedMemorySize, 131072) == hipSuccess;
  big &= hipFuncSetAttribute(reinterpret_cast<const void*>(&gemm256<2,256>),
                             hipFuncAttributeMaxDynamicSharedMemorySize, 131072) == hipSuccess;
  big &= hipFuncSetAttribute(reinterpret_cast<const void*>(&gemm256<1,128>),
                             hipFuncAttributeMaxDynamicSharedMemorySize, 98304) == hipSuccess;

  if (big){
    gemm256<0,256><<<dim3(MTOT/256, 3*D_EMB/256), 512, 131072, stream>>>(h1, WqkvT, MTOT, 3*D_EMB, D_EMB,
        bq, bk, bv, nullptr, Qb, Kb, VTb);
    attn_kernel<<<NB*NH*(NSEQ/128), 256, 0, stream>>>(Qb, Kb, VTb, attnC);
    gemm256<1,128><<<dim3(MTOT/256, D_EMB/128), 512, 98304, stream>>>(attnC, WpT, MTOT, D_EMB, D_EMB,
        bp, nullptr, nullptr, x, x1, nullptr, nullptr);
    ln_kernel<<<MTOT, 256, 0, stream>>>(x1, ln2g, ln2b, h2);
    gemm256<2,256><<<dim3(MTOT/256, DFF/256), 512, 131072, stream>>>(h2, W1T, MTOT, DFF, D_EMB,
        b1, nullptr, nullptr, nullptr, ffb, nullptr, nullptr);
    gemm256<1,128><<<dim3(MTOT/256, D_EMB/128), 512, 98304, stream>>>(ffb, W2T, MTOT, D_EMB, DFF,
        b2, nullptr, nullptr, x1, out, nullptr, nullptr);
  } else {
    gemm_bt<0><<<dim3(MTOT/BM, (3*D_EMB)/BN), 256, 0, stream>>>(h1, WqkvT, MTOT, 3*D_EMB, D_EMB,
        bq, bk, bv, nullptr, Qb, Kb, VTb);
    attn_kernel<<<NB*NH*(NSEQ/128), 256, 0, stream>>>(Qb, Kb, VTb, attnC);
    gemm_bt<1><<<dim3(MTOT/BM, D_EMB/BN), 256, 0, stream>>>(attnC, WpT, MTOT, D_EMB, D_EMB,
        bp, nullptr, nullptr, x, x1, nullptr, nullptr);
    ln_kernel<<<MTOT, 256, 0, stream>>>(x1, ln2g, ln2b, h2);
    gemm_bt<2><<<dim3(MTOT/BM, DFF/BN), 256, 0, stream>>>(h2, W1T, MTOT, DFF, D_EMB,
        b1, nullptr, nullptr, nullptr, ffb, nullptr, nullptr);
    gemm_bt<1><<<dim3(MTOT/BM, D_EMB/BN), 256, 0, stream>>>(ffb, W2T, MTOT, D_EMB, DFF,
        b2, nullptr, nullptr, x1, out, nullptr, nullptr);
  }
}

// Round 7
// 498.863 us; speedup vs baseline: 1.0121x; 1.0121x over previous
//
#include <hip/hip_runtime.h>
#include <cstdint>
#include <cstddef>

typedef unsigned short u16;
typedef __attribute__((ext_vector_type(4))) float f32x4;
typedef __attribute__((ext_vector_type(8))) short s16x8;

#define D_EMB 1024
#define NSEQ 1024
#define NB 8
#define NH 16
#define HS 64
#define DFF 4096
#define MTOT (NB*NSEQ)

__device__ __forceinline__ u16 f2bf(float f){
  unsigned u = __float_as_uint(f);
  u += 0x7FFFu + ((u >> 16) & 1u);     // round-to-nearest-even
  return (u16)(u >> 16);
}

__device__ __forceinline__ void gload_lds16(const void* g, void* l){
  __builtin_amdgcn_global_load_lds((const __attribute__((address_space(1))) void*)g,
                                   (__attribute__((address_space(3))) void*)l, 16, 0, 0);
}

#define WAITV(n) asm volatile("s_waitcnt vmcnt(" #n ")" ::: "memory")

// ---------------- tiled transpose + fp32->bf16 convert ----------------
__global__ void transpose_cvt(const float* __restrict__ in, u16* __restrict__ out,
                              int R, int C, size_t inStride, size_t outStride){
  __shared__ float t[32][33];
  const float* ip = in + (size_t)blockIdx.z * inStride;
  u16* op = out + (size_t)blockIdx.z * outStride;
  int c0 = blockIdx.x * 32, r0 = blockIdx.y * 32;
  int tx = threadIdx.x, ty = threadIdx.y;
#pragma unroll
  for (int j = 0; j < 32; j += 8)
    t[ty + j][tx] = ip[(size_t)(r0 + ty + j) * C + (c0 + tx)];
  __syncthreads();
#pragma unroll
  for (int j = 0; j < 32; j += 8)
    op[(size_t)(c0 + ty + j) * R + (r0 + tx)] = f2bf(t[tx][ty + j]);
}

// ---------------- LayerNorm (fp32 in, bf16 out) ----------------
__global__ __launch_bounds__(256) void ln_kernel(const float* __restrict__ x,
    const float* __restrict__ g, const float* __restrict__ bb, u16* __restrict__ out){
  int row = blockIdx.x;
  const float* xr = x + (size_t)row * D_EMB;
  int c = threadIdx.x * 4;
  f32x4 v = *(const f32x4*)(xr + c);
  float s1 = v[0] + v[1] + v[2] + v[3];
  float s2 = v[0]*v[0] + v[1]*v[1] + v[2]*v[2] + v[3]*v[3];
#pragma unroll
  for (int m = 32; m > 0; m >>= 1){ s1 += __shfl_xor(s1, m); s2 += __shfl_xor(s2, m); }
  __shared__ float ps1[4], ps2[4];
  int w = threadIdx.x >> 6;
  if ((threadIdx.x & 63) == 0){ ps1[w] = s1; ps2[w] = s2; }
  __syncthreads();
  s1 = ps1[0] + ps1[1] + ps1[2] + ps1[3];
  s2 = ps2[0] + ps2[1] + ps2[2] + ps2[3];
  float mu = s1 * (1.f / D_EMB);
  float var = s2 * (1.f / D_EMB) - mu * mu;
  float rs = rsqrtf(var + 1e-5f);
  ushort4 o;
  o.x = f2bf((v[0]-mu)*rs*g[c+0] + bb[c+0]);
  o.y = f2bf((v[1]-mu)*rs*g[c+1] + bb[c+1]);
  o.z = f2bf((v[2]-mu)*rs*g[c+2] + bb[c+2]);
  o.w = f2bf((v[3]-mu)*rs*g[c+3] + bb[c+3]);
  *(ushort4*)(out + (size_t)row * D_EMB + c) = o;
}

// ============ 256-row phased GEMM, BK=32, 4-deep prefetch ring ============
// C = A[M,K] * Bt[N,K]^T. 512 thr = 8 waves. Per K-tile: 2 phases x 16(8) MFMA.
// Ring: buf = kt&3; tile kt stages tile kt+3 (A in phase0, B in phase1).
// One counted vmcnt per tile; tail peeled (vmcnt(PL), vmcnt(0), none).
// LDS SWIZZLE (round-7): BK=32 rows are 64B, so linear chunks give an 8-way
// bank conflict on ds_read_b128 (quad = 4*(row&1)+chunk). Read chunk
// ch = (lg + (row>>1)) & 3 spreads the 16 lr-lanes over all 8 quads 2x each
// (2-way = free, m136). Staging keeps a LINEAR LDS dst (global_load_lds
// requirement) and fetches the inverse-permuted global chunk
// cg = ((tid&3) - ((srow>>1)&3)) & 3; rows r and r+128 share the same key.
template<int MODE, int BNT>
__global__ __launch_bounds__(512) void gemm256(
    const u16* __restrict__ A, const u16* __restrict__ Bt,
    int M, int N, int K,
    const float* __restrict__ bias0, const float* __restrict__ bias1,
    const float* __restrict__ bias2, const float* __restrict__ resid,
    void* __restrict__ o0, void* __restrict__ o1, void* __restrict__ o2)
{
  constexpr int BMT = 256;
  constexpr int WCN = BNT/64, WRN = 8/WCN;       // wave grid (cols, rows)
  constexpr int WROWS = BMT/WRN;                 // rows per wave (128 or 64)
  constexpr int RF = WROWS/16, RH = RF/2;        // row frags / per phase
  constexpr int ALD = 2;                         // A 16KB / (512*16B)
  constexpr int BLD = (BNT*32*2)/(512*16);       // 2 (BNT=256) or 1 (BNT=128)
  constexpr int PL  = ALD + BLD;                 // loads per tile
  constexpr int ABUF = BMT*32, BBUF = BNT*32;    // u16 per ring buffer
  extern __shared__ u16 lds[];
  u16* const Ab = lds;                           // [4][ABUF]
  u16* const Bb = lds + 4*ABUF;                  // [4][BBUF]

  const int tid = threadIdx.x;
  const int wid = tid>>6, lane = tid&63, lr = lane&15, lg = lane>>4;
  const int wr = wid/WCN, wc = wid%WCN;

  // XCD swizzle (nwg divisible by 8 for all our grids)
  const int gx = gridDim.x;
  const int nwg = gx * gridDim.y;
  const int bid = blockIdx.x + blockIdx.y*gx;
  const int wg = (bid&7)*(nwg>>3) + (bid>>3);
  const int m0 = (wg % gx) * BMT;
  const int n0 = (wg / gx) * BNT;

  const int nkt = K/32;
  const int srow = tid>>2;                                   // staging row
  const int scs = (((tid&3) - ((srow>>1)&3)) & 3) * 8;       // inv-swizzled src chunk

  auto stageA = [&](int kt3){
    const u16* src = A + (size_t)(m0 + srow)*K + kt3*32 + scs;
    u16* dst = Ab + (kt3&3)*ABUF + tid*8;
    gload_lds16(src, dst);
    gload_lds16(src + (size_t)128*K, dst + 4096);
  };
  auto stageB = [&](int kt3){
    const u16* src = Bt + (size_t)(n0 + srow)*K + kt3*32 + scs;
    u16* dst = Bb + (kt3&3)*BBUF + tid*8;
    gload_lds16(src, dst);
    if constexpr (BLD == 2) gload_lds16(src + (size_t)128*K, dst + 4096);
  };
  auto rdA = [&](int kt, int fm) -> s16x8 {
    const int row = wr*WROWS + fm*16 + lr;
    const int ch = (lg + (row>>1)) & 3;
    return *(const s16x8*)&Ab[(kt&3)*ABUF + row*32 + ch*8];
  };
  auto rdB = [&](int kt, int fn) -> s16x8 {
    const int row = wc*64 + fn*16 + lr;
    const int ch = (lg + (row>>1)) & 3;
    return *(const s16x8*)&Bb[(kt&3)*BBUF + row*32 + ch*8];
  };

  f32x4 acc[RF][4];
#pragma unroll
  for (int i = 0; i < RF; i++)
#pragma unroll
    for (int j = 0; j < 4; j++) acc[i][j] = {0.f,0.f,0.f,0.f};

  // tile body. wsel: 2 = steady (drain to 2*PL), 1 = drain to PL,
  // 0 = drain to 0, -1 = last tile (no wait, no trailing barrier).
  auto tile = [&](int kt, bool doStage, int wsel){
    s16x8 af[RH], bf[4];
    // ---- phase 0: A-low frags + all B frags ----
#pragma unroll
    for (int j = 0; j < RH; ++j) af[j] = rdA(kt, j);
#pragma unroll
    for (int f = 0; f < 4;  ++f) bf[f] = rdB(kt, f);
    if (doStage) stageA(kt+3);
    __builtin_amdgcn_s_barrier();
    asm volatile("s_waitcnt lgkmcnt(0)" ::: "memory");
    __builtin_amdgcn_sched_barrier(0);
    __builtin_amdgcn_s_setprio(1);
#pragma unroll
    for (int j = 0; j < RH; ++j)
#pragma unroll
      for (int f = 0; f < 4; ++f)
        acc[j][f] = __builtin_amdgcn_mfma_f32_16x16x32_bf16(af[j], bf[f], acc[j][f], 0, 0, 0);
    __builtin_amdgcn_s_setprio(0);
    __builtin_amdgcn_s_barrier();
    // ---- phase 1: A-high frags, reuse bf ----
#pragma unroll
    for (int j = 0; j < RH; ++j) af[j] = rdA(kt, RH + j);
    if (doStage) stageB(kt+3);
    __builtin_amdgcn_s_barrier();
    asm volatile("s_waitcnt lgkmcnt(0)" ::: "memory");
    __builtin_amdgcn_sched_barrier(0);
    __builtin_amdgcn_s_setprio(1);
#pragma unroll
    for (int j = 0; j < RH; ++j)
#pragma unroll
      for (int f = 0; f < 4; ++f)
        acc[RH+j][f] = __builtin_amdgcn_mfma_f32_16x16x32_bf16(af[j], bf[f], acc[RH+j][f], 0, 0, 0);
    __builtin_amdgcn_s_setprio(0);
    if (wsel == 2){
      if constexpr (PL == 4) WAITV(8); else WAITV(6);
      __builtin_amdgcn_s_barrier();
    } else if (wsel == 1){
      if constexpr (PL == 4) WAITV(4); else WAITV(3);
      __builtin_amdgcn_s_barrier();
    } else if (wsel == 0){
      WAITV(0);
      __builtin_amdgcn_s_barrier();
    }
  };

  // prologue: stage tiles 0,1,2; certify tile 0 (drain to 2*PL)
  stageA(0); stageB(0);
  stageA(1); stageB(1);
  stageA(2); stageB(2);
  if constexpr (PL == 4) WAITV(8); else WAITV(6);
  __builtin_amdgcn_s_barrier();

  for (int kt = 0; kt < nkt - 3; ++kt) tile(kt, true, 2);
  tile(nkt-3, false, 1);
  tile(nkt-2, false, 0);
  tile(nkt-1, false, -1);

  // epilogue
#pragma unroll
  for (int fm = 0; fm < RF; fm++){
    const int gmb = m0 + wr*WROWS + fm*16 + lg*4;
#pragma unroll
    for (int fn = 0; fn < 4; fn++){
      const int gn = n0 + wc*64 + fn*16 + lr;
#pragma unroll
      for (int i = 0; i < 4; i++){
        const int gm = gmb + i;
        float v = acc[fm][fn][i];
        if (MODE == 0){
          const int cls = gn >> 10, nn = gn & 1023;
          if (cls == 0)      ((u16*)o0)[(size_t)gm * D_EMB + nn] = f2bf(v + bias0[nn]);
          else if (cls == 1) ((u16*)o1)[(size_t)gm * D_EMB + nn] = f2bf(v + bias1[nn]);
          else {
            const int hh = nn >> 6, ss = nn & 63, bb = gm >> 10, tt = gm & 1023;
            ((u16*)o2)[(((size_t)(bb * NH + hh)) * HS + ss) * NSEQ + tt] = f2bf(v + bias2[nn]);
          }
        } else if (MODE == 1){
          ((float*)o0)[(size_t)gm * N + gn] = resid[(size_t)gm * N + gn] + v + bias0[gn];
        } else {
          float y = v + bias0[gn];
          y = y > 0.f ? y : 0.01f * y;
          ((u16*)o0)[(size_t)gm * N + gn] = f2bf(y);
        }
      }
    }
  }
}

// ---------------- fallback GEMM (proven round-3 128x128) ----------------
#define BM 128
#define BN 128
#define BK 32
template<int MODE>
__global__ __launch_bounds__(256) void gemm_bt(
    const u16* __restrict__ A, const u16* __restrict__ Bt,
    int M, int N, int K,
    const float* __restrict__ bias0, const float* __restrict__ bias1,
    const float* __restrict__ bias2, const float* __restrict__ resid,
    void* __restrict__ o0, void* __restrict__ o1, void* __restrict__ o2)
{
  __shared__ alignas(16) u16 Al[2][BM*BK];
  __shared__ alignas(16) u16 Bl[2][BN*BK];
  const int tid = threadIdx.x;
  const int m0 = blockIdx.x * BM, n0 = blockIdx.y * BN;
  const int wid = tid >> 6, lane = tid & 63;
  const int wm = (wid >> 1) * 64, wn = (wid & 1) * 64;
  const int lr = lane & 15, lg = lane >> 4;

  f32x4 acc[4][4];
#pragma unroll
  for (int i = 0; i < 4; i++)
#pragma unroll
    for (int j = 0; j < 4; j++) acc[i][j] = {0.f,0.f,0.f,0.f};

  const int nk = K / BK;
  const int arow = tid >> 2, akg = tid & 3;

  auto stage = [&](int bufi, int kt){
    const int k0 = kt * BK;
    const u16* ap = A  + (size_t)(m0 + arow) * K + k0 + akg * 8;
    gload_lds16(ap,                  &Al[bufi][tid * 8]);
    gload_lds16(ap + (size_t)64 * K, &Al[bufi][2048 + tid * 8]);
    const u16* bp = Bt + (size_t)(n0 + arow) * K + k0 + akg * 8;
    gload_lds16(bp,                  &Bl[bufi][tid * 8]);
    gload_lds16(bp + (size_t)64 * K, &Bl[bufi][2048 + tid * 8]);
  };

  stage(0, 0);
  for (int kt = 0; kt < nk; ++kt){
    __syncthreads();
    if (kt + 1 < nk) stage((kt + 1) & 1, kt + 1);
    const int bufi = kt & 1;
    s16x8 af[4], bfr[4];
#pragma unroll
    for (int i = 0; i < 4; i++){
      af[i]  = *(const s16x8*)&Al[bufi][(wm + i*16 + lr) * BK + lg * 8];
      bfr[i] = *(const s16x8*)&Bl[bufi][(wn + i*16 + lr) * BK + lg * 8];
    }
#pragma unroll
    for (int i = 0; i < 4; i++)
#pragma unroll
      for (int j = 0; j < 4; j++)
        acc[i][j] = __builtin_amdgcn_mfma_f32_16x16x32_bf16(af[i], bfr[j], acc[i][j], 0, 0, 0);
  }

#pragma unroll
  for (int fm = 0; fm < 4; fm++){
    const int gmb = m0 + wm + fm * 16 + lg * 4;
#pragma unroll
    for (int fn = 0; fn < 4; fn++){
      const int gn = n0 + wn + fn * 16 + lr;
#pragma unroll
      for (int i = 0; i < 4; i++){
        const int gm = gmb + i;
        float v = acc[fm][fn][i];
        if (MODE == 0){
          const int cls = gn >> 10, nn = gn & 1023;
          if (cls == 0)      ((u16*)o0)[(size_t)gm * D_EMB + nn] = f2bf(v + bias0[nn]);
          else if (cls == 1) ((u16*)o1)[(size_t)gm * D_EMB + nn] = f2bf(v + bias1[nn]);
          else {
            const int hh = nn >> 6, ss = nn & 63, bb = gm >> 10, tt = gm & 1023;
            ((u16*)o2)[(((size_t)(bb * NH + hh)) * HS + ss) * NSEQ + tt] = f2bf(v + bias2[nn]);
          }
        } else if (MODE == 1){
          ((float*)o0)[(size_t)gm * N + gn] = resid[(size_t)gm * N + gn] + v + bias0[gn];
        } else {
          float y = v + bias0[gn];
          y = y > 0.f ? y : 0.01f * y;
          ((u16*)o0)[(size_t)gm * N + gn] = f2bf(y);
        }
      }
    }
  }
}

// ---------------- flash attention (round-3, unchanged) ----------------
__global__ __launch_bounds__(256) void attn_kernel(
    const u16* __restrict__ Qb, const u16* __restrict__ Kb, const u16* __restrict__ VT,
    u16* __restrict__ attnC)
{
  const int bid = blockIdx.x;
  const int bh = bid & 127, qt = bid >> 7;
  const int b = bh >> 4, h = bh & 15;
  const int tid = threadIdx.x, w = tid >> 6, lane = tid & 63;
  const int lr = lane & 15, lg = lane >> 4;
  const int q0 = qt * 128 + w * 32;

  __shared__ alignas(16) u16 Kl[2][64*64];
  __shared__ alignas(16) u16 Vl[2][64*64];
  __shared__ alignas(16) u16 Pl[4][32][72];

  const int srow = tid >> 3, scg = tid & 7;
  const u16* kbase = Kb + (size_t)(b * NSEQ) * D_EMB + h * HS;
  const u16* vbase = VT + ((size_t)(b * NH + h)) * HS * NSEQ;

  auto stage = [&](int buf, int kt){
    const int tk = kt * 64;
#pragma unroll
    for (int p = 0; p < 2; ++p){
      const int row = srow + p * 32;
      const int sc = scg ^ (row & 7);
      gload_lds16(kbase + (size_t)(tk + row) * D_EMB + sc * 8, &Kl[buf][(p * 256 + tid) * 8]);
      gload_lds16(vbase + (size_t)row * NSEQ + tk + sc * 8,    &Vl[buf][(p * 256 + tid) * 8]);
    }
  };

  s16x8 aq[2][2];
#pragma unroll
  for (int rb = 0; rb < 2; rb++)
#pragma unroll
    for (int kh = 0; kh < 2; kh++)
      aq[rb][kh] = *(const s16x8*)(Qb + (size_t)(b * NSEQ + q0 + rb * 16 + lr) * D_EMB
                                   + h * HS + kh * 32 + lg * 8);

  float m_i[2][4], l_i[2][4];
  f32x4 zero = {0.f, 0.f, 0.f, 0.f};
  f32x4 ao[2][4];
#pragma unroll
  for (int rb = 0; rb < 2; rb++)
#pragma unroll
    for (int i = 0; i < 4; i++){ m_i[rb][i] = -1e30f; l_i[rb][i] = 0.f; ao[rb][i] = zero; }

  const float scale = 0.125f;
  const int rsw = lr & 7;

  stage(0, 0);
  for (int kt = 0; kt < NSEQ / 64; ++kt){
    __syncthreads();
    if (kt + 1 < NSEQ / 64) stage((kt + 1) & 1, kt + 1);
    const int cur = kt & 1;

    f32x4 sv[2][4];
#pragma unroll
    for (int rb = 0; rb < 2; rb++)
#pragma unroll
      for (int fn = 0; fn < 4; fn++) sv[rb][fn] = zero;
#pragma unroll
    for (int fn = 0; fn < 4; fn++){
      const int krow = fn * 16 + lr;
#pragma unroll
      for (int kh = 0; kh < 2; kh++){
        const int chunk = (kh * 4 + lg) ^ rsw;
        s16x8 kf = *(const s16x8*)&Kl[cur][krow * 64 + chunk * 8];
        sv[0][fn] = __builtin_amdgcn_mfma_f32_16x16x32_bf16(aq[0][kh], kf, sv[0][fn], 0, 0, 0);
        sv[1][fn] = __builtin_amdgcn_mfma_f32_16x16x32_bf16(aq[1][kh], kf, sv[1][fn], 0, 0, 0);
      }
    }

#pragma unroll
    for (int rb = 0; rb < 2; rb++){
      float p[4][4];
#pragma unroll
      for (int i = 0; i < 4; i++){
        float s0 = sv[rb][0][i] * scale, s1 = sv[rb][1][i] * scale;
        float s2 = sv[rb][2][i] * scale, s3 = sv[rb][3][i] * scale;
        float rmax = fmaxf(fmaxf(s0, s1), fmaxf(s2, s3));
#pragma unroll
        for (int mm = 8; mm > 0; mm >>= 1) rmax = fmaxf(rmax, __shfl_xor(rmax, mm));
        float mnew = fmaxf(m_i[rb][i], rmax);
        float fac = __expf(m_i[rb][i] - mnew);
        float p0 = __expf(s0 - mnew), p1 = __expf(s1 - mnew);
        float p2 = __expf(s2 - mnew), p3 = __expf(s3 - mnew);
        p[0][i] = p0; p[1][i] = p1; p[2][i] = p2; p[3][i] = p3;
        float rs = (p0 + p1) + (p2 + p3);
#pragma unroll
        for (int mm = 8; mm > 0; mm >>= 1) rs += __shfl_xor(rs, mm);
        l_i[rb][i] = l_i[rb][i] * fac + rs;
        m_i[rb][i] = mnew;
#pragma unroll
        for (int fn = 0; fn < 4; fn++) ao[rb][fn][i] *= fac;
      }
#pragma unroll
      for (int fn = 0; fn < 4; fn++)
#pragma unroll
        for (int i = 0; i < 4; i++)
          Pl[w][rb * 16 + lg * 4 + i][fn * 16 + lr] = f2bf(p[fn][i]);
    }

    s16x8 vf[4][2];
#pragma unroll
    for (int fn = 0; fn < 4; fn++){
      const int vrow = fn * 16 + lr;
#pragma unroll
      for (int kh = 0; kh < 2; kh++){
        const int chunk = (kh * 4 + lg) ^ rsw;
        vf[fn][kh] = *(const s16x8*)&Vl[cur][vrow * 64 + chunk * 8];
      }
    }
#pragma unroll
    for (int rb = 0; rb < 2; rb++){
      s16x8 pa0 = *(const s16x8*)&Pl[w][rb * 16 + lr][lg * 8];
      s16x8 pa1 = *(const s16x8*)&Pl[w][rb * 16 + lr][32 + lg * 8];
#pragma unroll
      for (int fn = 0; fn < 4; fn++){
        ao[rb][fn] = __builtin_amdgcn_mfma_f32_16x16x32_bf16(pa0, vf[fn][0], ao[rb][fn], 0, 0, 0);
        ao[rb][fn] = __builtin_amdgcn_mfma_f32_16x16x32_bf16(pa1, vf[fn][1], ao[rb][fn], 0, 0, 0);
      }
    }
  }

#pragma unroll
  for (int rb = 0; rb < 2; rb++)
#pragma unroll
    for (int fn = 0; fn < 4; fn++)
#pragma unroll
      for (int i = 0; i < 4; i++){
        float v = ao[rb][fn][i] / l_i[rb][i];
        attnC[(size_t)(b * NSEQ + q0 + rb * 16 + lg * 4 + i) * D_EMB + h * HS + fn * 16 + lr] = f2bf(v);
      }
}

// ---------------- host ----------------
extern "C" void kernel_launch(void* const* d_in, const int* in_sizes, int n_in,
                              void* d_out, int out_size, void* d_ws, size_t ws_size,
                              hipStream_t stream)
{
  const float* x    = (const float*)d_in[0];
  const float* Wq   = (const float*)d_in[1];
  const float* bq   = (const float*)d_in[2];
  const float* Wk   = (const float*)d_in[3];
  const float* bk   = (const float*)d_in[4];
  const float* Wv   = (const float*)d_in[5];
  const float* bv   = (const float*)d_in[6];
  const float* Wp   = (const float*)d_in[7];
  const float* bp   = (const float*)d_in[8];
  const float* W1   = (const float*)d_in[9];
  const float* b1   = (const float*)d_in[10];
  const float* W2   = (const float*)d_in[11];
  const float* b2   = (const float*)d_in[12];
  const float* ln1g = (const float*)d_in[13];
  const float* ln1b = (const float*)d_in[14];
  const float* ln2g = (const float*)d_in[15];
  const float* ln2b = (const float*)d_in[16];
  float* out = (float*)d_out;

  char* ws = (char*)d_ws;
  size_t off = 0;
  auto mk = [&](size_t bytes)->void*{ void* p = ws + off; off += (bytes + 255) & ~(size_t)255; return p; };
  u16*  h1    = (u16*) mk((size_t)MTOT * D_EMB * 2);
  u16*  Qb    = (u16*) mk((size_t)MTOT * D_EMB * 2);
  u16*  Kb    = (u16*) mk((size_t)MTOT * D_EMB * 2);
  u16*  VTb   = (u16*) mk((size_t)MTOT * D_EMB * 2);
  u16*  attnC = (u16*) mk((size_t)MTOT * D_EMB * 2);
  float* x1   = (float*)mk((size_t)MTOT * D_EMB * 4);
  u16*  h2    = (u16*) mk((size_t)MTOT * D_EMB * 2);
  u16*  ffb   = (u16*) mk((size_t)MTOT * DFF * 2);
  u16*  WqkvT = (u16*) mk((size_t)3 * D_EMB * D_EMB * 2);
  u16*  WpT   = (u16*) mk((size_t)D_EMB * D_EMB * 2);
  u16*  W1T   = (u16*) mk((size_t)D_EMB * DFF * 2);
  u16*  W2T   = (u16*) mk((size_t)D_EMB * DFF * 2);

  dim3 tb(32, 8, 1);
  transpose_cvt<<<dim3(HS/32, D_EMB/32, NH), tb, 0, stream>>>(Wq, WqkvT,                         D_EMB, HS, (size_t)D_EMB*HS, (size_t)HS*D_EMB);
  transpose_cvt<<<dim3(HS/32, D_EMB/32, NH), tb, 0, stream>>>(Wk, WqkvT + (size_t)D_EMB*D_EMB,   D_EMB, HS, (size_t)D_EMB*HS, (size_t)HS*D_EMB);
  transpose_cvt<<<dim3(HS/32, D_EMB/32, NH), tb, 0, stream>>>(Wv, WqkvT + (size_t)2*D_EMB*D_EMB, D_EMB, HS, (size_t)D_EMB*HS, (size_t)HS*D_EMB);
  transpose_cvt<<<dim3(D_EMB/32, D_EMB/32, 1), tb, 0, stream>>>(Wp, WpT,  D_EMB, D_EMB, 0, 0);
  transpose_cvt<<<dim3(DFF/32,  D_EMB/32, 1), tb, 0, stream>>>(W1, W1T,  D_EMB, DFF,   0, 0);
  transpose_cvt<<<dim3(D_EMB/32, DFF/32,  1), tb, 0, stream>>>(W2, W2T,  DFF,   D_EMB, 0, 0);

  ln_kernel<<<MTOT, 256, 0, stream>>>(x, ln1g, ln1b, h1);

  // opt-in to >64KB dynamic LDS; fall back to proven 128^2 GEMM on failure
  bool big = true;
  big &= hipFuncSetAttribute(reinterpret_cast<const void*>(&gemm256<0,256>),
                             hipFuncAttributeMaxDynamicSharedMemorySize, 131072) == hipSuccess;
  big &= hipFuncSetAttribute(reinterpret_cast<const void*>(&gemm256<2,256>),
                             hipFuncAttributeMaxDynamicSharedMemorySize, 131072) == hipSuccess;
  big &= hipFuncSetAttribute(reinterpret_cast<const void*>(&gemm256<1,128>),
                             hipFuncAttributeMaxDynamicSharedMemorySize, 98304) == hipSuccess;

  if (big){
    gemm256<0,256><<<dim3(MTOT/256, 3*D_EMB/256), 512, 131072, stream>>>(h1, WqkvT, MTOT, 3*D_EMB, D_EMB,
        bq, bk, bv, nullptr, Qb, Kb, VTb);
    attn_kernel<<<NB*NH*(NSEQ/128), 256, 0, stream>>>(Qb, Kb, VTb, attnC);
    gemm256<1,128><<<dim3(MTOT/256, D_EMB/128), 512, 98304, stream>>>(attnC, WpT, MTOT, D_EMB, D_EMB,
        bp, nullptr, nullptr, x, x1, nullptr, nullptr);
    ln_kernel<<<MTOT, 256, 0, stream>>>(x1, ln2g, ln2b, h2);
    gemm256<2,256><<<dim3(MTOT/256, DFF/256), 512, 131072, stream>>>(h2, W1T, MTOT, DFF, D_EMB,
        b1, nullptr, nullptr, nullptr, ffb, nullptr, nullptr);
    gemm256<1,128><<<dim3(MTOT/256, D_EMB/128), 512, 98304, stream>>>(ffb, W2T, MTOT, D_EMB, DFF,
        b2, nullptr, nullptr, x1, out, nullptr, nullptr);
  } else {
    gemm_bt<0><<<dim3(MTOT/BM, (3*D_EMB)/BN), 256, 0, stream>>>(h1, WqkvT, MTOT, 3*D_EMB, D_EMB,
        bq, bk, bv, nullptr, Qb, Kb, VTb);
    attn_kernel<<<NB*NH*(NSEQ/128), 256, 0, stream>>>(Qb, Kb, VTb, attnC);
    gemm_bt<1><<<dim3(MTOT/BM, D_EMB/BN), 256, 0, stream>>>(attnC, WpT, MTOT, D_EMB, D_EMB,
        bp, nullptr, nullptr, x, x1, nullptr, nullptr);
    ln_kernel<<<MTOT, 256, 0, stream>>>(x1, ln2g, ln2b, h2);
    gemm_bt<2><<<dim3(MTOT/BM, DFF/BN), 256, 0, stream>>>(h2, W1T, MTOT, DFF, D_EMB,
        b1, nullptr, nullptr, nullptr, ffb, nullptr, nullptr);
    gemm_bt<1><<<dim3(MTOT/BM, D_EMB/BN), 256, 0, stream>>>(ffb, W2T, MTOT, D_EMB, DFF,
        b2, nullptr, nullptr, x1, out, nullptr, nullptr);
  }
}

// Round 8
// 497.125 us; speedup vs baseline: 1.0156x; 1.0035x over previous
//
#include <hip/hip_runtime.h>
#include <cstdint>
#include <cstddef>

typedef unsigned short u16;
typedef __attribute__((ext_vector_type(4))) float f32x4;
typedef __attribute__((ext_vector_type(8))) short s16x8;

#define D_EMB 1024
#define NSEQ 1024
#define NB 8
#define NH 16
#define HS 64
#define DFF 4096
#define MTOT (NB*NSEQ)

__device__ __forceinline__ u16 f2bf(float f){
  unsigned u = __float_as_uint(f);
  u += 0x7FFFu + ((u >> 16) & 1u);     // round-to-nearest-even
  return (u16)(u >> 16);
}

__device__ __forceinline__ void gload_lds16(const void* g, void* l){
  __builtin_amdgcn_global_load_lds((const __attribute__((address_space(1))) void*)g,
                                   (__attribute__((address_space(3))) void*)l, 16, 0, 0);
}

#define WAITV(n) asm volatile("s_waitcnt vmcnt(" #n ")" ::: "memory")

// ---------------- tiled transpose + fp32->bf16 convert ----------------
__global__ void transpose_cvt(const float* __restrict__ in, u16* __restrict__ out,
                              int R, int C, size_t inStride, size_t outStride){
  __shared__ float t[32][33];
  const float* ip = in + (size_t)blockIdx.z * inStride;
  u16* op = out + (size_t)blockIdx.z * outStride;
  int c0 = blockIdx.x * 32, r0 = blockIdx.y * 32;
  int tx = threadIdx.x, ty = threadIdx.y;
#pragma unroll
  for (int j = 0; j < 32; j += 8)
    t[ty + j][tx] = ip[(size_t)(r0 + ty + j) * C + (c0 + tx)];
  __syncthreads();
#pragma unroll
  for (int j = 0; j < 32; j += 8)
    op[(size_t)(c0 + ty + j) * R + (r0 + tx)] = f2bf(t[tx][ty + j]);
}

// ---------------- LayerNorm (fp32 in, bf16 out) ----------------
__global__ __launch_bounds__(256) void ln_kernel(const float* __restrict__ x,
    const float* __restrict__ g, const float* __restrict__ bb, u16* __restrict__ out){
  int row = blockIdx.x;
  const float* xr = x + (size_t)row * D_EMB;
  int c = threadIdx.x * 4;
  f32x4 v = *(const f32x4*)(xr + c);
  float s1 = v[0] + v[1] + v[2] + v[3];
  float s2 = v[0]*v[0] + v[1]*v[1] + v[2]*v[2] + v[3]*v[3];
#pragma unroll
  for (int m = 32; m > 0; m >>= 1){ s1 += __shfl_xor(s1, m); s2 += __shfl_xor(s2, m); }
  __shared__ float ps1[4], ps2[4];
  int w = threadIdx.x >> 6;
  if ((threadIdx.x & 63) == 0){ ps1[w] = s1; ps2[w] = s2; }
  __syncthreads();
  s1 = ps1[0] + ps1[1] + ps1[2] + ps1[3];
  s2 = ps2[0] + ps2[1] + ps2[2] + ps2[3];
  float mu = s1 * (1.f / D_EMB);
  float var = s2 * (1.f / D_EMB) - mu * mu;
  float rs = rsqrtf(var + 1e-5f);
  ushort4 o;
  o.x = f2bf((v[0]-mu)*rs*g[c+0] + bb[c+0]);
  o.y = f2bf((v[1]-mu)*rs*g[c+1] + bb[c+1]);
  o.z = f2bf((v[2]-mu)*rs*g[c+2] + bb[c+2]);
  o.w = f2bf((v[3]-mu)*rs*g[c+3] + bb[c+3]);
  *(ushort4*)(out + (size_t)row * D_EMB + c) = o;
}

// ============ 256-row GEMM, BK=32, 4-deep ring, ONE barrier/tile ============
// C = A[M,K] * Bt[N,K]^T. 512 thr = 8 waves.
// Round-8 schedule surgery: each K-tile is a single region
//   {ds_read all frags(buf kt); stage kt+3; 2x MFMA cluster; waitv; barrier}
// Hazard proof: staging targets buf (kt+3)&3=(kt-1)&3 whose readers all passed
// tile kt-1's closing barrier; reads target buf kt&3 (untouched). waitv's
// "memory" clobber stops next-tile ds_reads hoisting above certification;
// the single barrier makes kt+1's staging (from ALL waves) visible.
// No asm lgkmcnt / sched_barrier: compiler emits counted lgkmcnt (m97).
// Tail peeled: wsel 2=steady drain-to-2PL, 1=PL, 0=0, -1=last (no wait).
template<int MODE, int BNT>
__global__ __launch_bounds__(512) void gemm256(
    const u16* __restrict__ A, const u16* __restrict__ Bt,
    int M, int N, int K,
    const float* __restrict__ bias0, const float* __restrict__ bias1,
    const float* __restrict__ bias2, const float* __restrict__ resid,
    void* __restrict__ o0, void* __restrict__ o1, void* __restrict__ o2)
{
  constexpr int BMT = 256;
  constexpr int WCN = BNT/64, WRN = 8/WCN;       // wave grid (cols, rows)
  constexpr int WROWS = BMT/WRN;                 // rows per wave (128 or 64)
  constexpr int RF = WROWS/16, RH = RF/2;        // row frags / per cluster
  constexpr int ALD = 2;                         // A 16KB / (512*16B)
  constexpr int BLD = (BNT*32*2)/(512*16);       // 2 (BNT=256) or 1 (BNT=128)
  constexpr int PL  = ALD + BLD;                 // loads per tile
  constexpr int ABUF = BMT*32, BBUF = BNT*32;    // u16 per ring buffer
  extern __shared__ u16 lds[];
  u16* const Ab = lds;                           // [4][ABUF]
  u16* const Bb = lds + 4*ABUF;                  // [4][BBUF]

  const int tid = threadIdx.x;
  const int wid = tid>>6, lane = tid&63, lr = lane&15, lg = lane>>4;
  const int wr = wid/WCN, wc = wid%WCN;

  // XCD swizzle (nwg divisible by 8 for all our grids)
  const int gx = gridDim.x;
  const int nwg = gx * gridDim.y;
  const int bid = blockIdx.x + blockIdx.y*gx;
  const int wg = (bid&7)*(nwg>>3) + (bid>>3);
  const int m0 = (wg % gx) * BMT;
  const int n0 = (wg / gx) * BNT;

  const int nkt = K/32;
  const int srow = tid>>2;                                   // staging row
  const int scs = (((tid&3) - ((srow>>1)&3)) & 3) * 8;       // inv-swizzled src chunk

  auto stageA = [&](int kt3){
    const u16* src = A + (size_t)(m0 + srow)*K + kt3*32 + scs;
    u16* dst = Ab + (kt3&3)*ABUF + tid*8;
    gload_lds16(src, dst);
    gload_lds16(src + (size_t)128*K, dst + 4096);
  };
  auto stageB = [&](int kt3){
    const u16* src = Bt + (size_t)(n0 + srow)*K + kt3*32 + scs;
    u16* dst = Bb + (kt3&3)*BBUF + tid*8;
    gload_lds16(src, dst);
    if constexpr (BLD == 2) gload_lds16(src + (size_t)128*K, dst + 4096);
  };
  auto rdA = [&](int kt, int fm) -> s16x8 {
    const int row = wr*WROWS + fm*16 + lr;
    const int ch = (lg + (row>>1)) & 3;
    return *(const s16x8*)&Ab[(kt&3)*ABUF + row*32 + ch*8];
  };
  auto rdB = [&](int kt, int fn) -> s16x8 {
    const int row = wc*64 + fn*16 + lr;
    const int ch = (lg + (row>>1)) & 3;
    return *(const s16x8*)&Bb[(kt&3)*BBUF + row*32 + ch*8];
  };

  f32x4 acc[RF][4];
#pragma unroll
  for (int i = 0; i < RF; i++)
#pragma unroll
    for (int j = 0; j < 4; j++) acc[i][j] = {0.f,0.f,0.f,0.f};

  auto tile = [&](int kt, bool doStage, int wsel){
    s16x8 af[RH], bf[4];
#pragma unroll
    for (int f = 0; f < 4;  ++f) bf[f] = rdB(kt, f);
#pragma unroll
    for (int j = 0; j < RH; ++j) af[j] = rdA(kt, j);
    if (doStage){ stageA(kt+3); stageB(kt+3); }
    __builtin_amdgcn_s_setprio(1);
#pragma unroll
    for (int j = 0; j < RH; ++j)
#pragma unroll
      for (int f = 0; f < 4; ++f)
        acc[j][f] = __builtin_amdgcn_mfma_f32_16x16x32_bf16(af[j], bf[f], acc[j][f], 0, 0, 0);
    __builtin_amdgcn_s_setprio(0);
#pragma unroll
    for (int j = 0; j < RH; ++j) af[j] = rdA(kt, RH + j);
    __builtin_amdgcn_s_setprio(1);
#pragma unroll
    for (int j = 0; j < RH; ++j)
#pragma unroll
      for (int f = 0; f < 4; ++f)
        acc[RH+j][f] = __builtin_amdgcn_mfma_f32_16x16x32_bf16(af[j], bf[f], acc[RH+j][f], 0, 0, 0);
    __builtin_amdgcn_s_setprio(0);
    if (wsel == 2){
      if constexpr (PL == 4) WAITV(8); else WAITV(6);
    } else if (wsel == 1){
      if constexpr (PL == 4) WAITV(4); else WAITV(3);
    } else if (wsel == 0){
      WAITV(0);
    }
    if (wsel >= 0) __builtin_amdgcn_s_barrier();
  };

  // prologue: stage tiles 0,1,2; certify tile 0 (drain to 2*PL)
  stageA(0); stageB(0);
  stageA(1); stageB(1);
  stageA(2); stageB(2);
  if constexpr (PL == 4) WAITV(8); else WAITV(6);
  __builtin_amdgcn_s_barrier();

  for (int kt = 0; kt < nkt - 3; ++kt) tile(kt, true, 2);
  tile(nkt-3, false, 1);
  tile(nkt-2, false, 0);
  tile(nkt-1, false, -1);

  // epilogue
#pragma unroll
  for (int fm = 0; fm < RF; fm++){
    const int gmb = m0 + wr*WROWS + fm*16 + lg*4;
#pragma unroll
    for (int fn = 0; fn < 4; fn++){
      const int gn = n0 + wc*64 + fn*16 + lr;
#pragma unroll
      for (int i = 0; i < 4; i++){
        const int gm = gmb + i;
        float v = acc[fm][fn][i];
        if (MODE == 0){
          const int cls = gn >> 10, nn = gn & 1023;
          if (cls == 0)      ((u16*)o0)[(size_t)gm * D_EMB + nn] = f2bf(v + bias0[nn]);
          else if (cls == 1) ((u16*)o1)[(size_t)gm * D_EMB + nn] = f2bf(v + bias1[nn]);
          else {
            const int hh = nn >> 6, ss = nn & 63, bb = gm >> 10, tt = gm & 1023;
            ((u16*)o2)[(((size_t)(bb * NH + hh)) * HS + ss) * NSEQ + tt] = f2bf(v + bias2[nn]);
          }
        } else if (MODE == 1){
          ((float*)o0)[(size_t)gm * N + gn] = resid[(size_t)gm * N + gn] + v + bias0[gn];
        } else {
          float y = v + bias0[gn];
          y = y > 0.f ? y : 0.01f * y;
          ((u16*)o0)[(size_t)gm * N + gn] = f2bf(y);
        }
      }
    }
  }
}

// ---------------- fallback GEMM (proven round-3 128x128) ----------------
#define BM 128
#define BN 128
#define BK 32
template<int MODE>
__global__ __launch_bounds__(256) void gemm_bt(
    const u16* __restrict__ A, const u16* __restrict__ Bt,
    int M, int N, int K,
    const float* __restrict__ bias0, const float* __restrict__ bias1,
    const float* __restrict__ bias2, const float* __restrict__ resid,
    void* __restrict__ o0, void* __restrict__ o1, void* __restrict__ o2)
{
  __shared__ alignas(16) u16 Al[2][BM*BK];
  __shared__ alignas(16) u16 Bl[2][BN*BK];
  const int tid = threadIdx.x;
  const int m0 = blockIdx.x * BM, n0 = blockIdx.y * BN;
  const int wid = tid >> 6, lane = tid & 63;
  const int wm = (wid >> 1) * 64, wn = (wid & 1) * 64;
  const int lr = lane & 15, lg = lane >> 4;

  f32x4 acc[4][4];
#pragma unroll
  for (int i = 0; i < 4; i++)
#pragma unroll
    for (int j = 0; j < 4; j++) acc[i][j] = {0.f,0.f,0.f,0.f};

  const int nk = K / BK;
  const int arow = tid >> 2, akg = tid & 3;

  auto stage = [&](int bufi, int kt){
    const int k0 = kt * BK;
    const u16* ap = A  + (size_t)(m0 + arow) * K + k0 + akg * 8;
    gload_lds16(ap,                  &Al[bufi][tid * 8]);
    gload_lds16(ap + (size_t)64 * K, &Al[bufi][2048 + tid * 8]);
    const u16* bp = Bt + (size_t)(n0 + arow) * K + k0 + akg * 8;
    gload_lds16(bp,                  &Bl[bufi][tid * 8]);
    gload_lds16(bp + (size_t)64 * K, &Bl[bufi][2048 + tid * 8]);
  };

  stage(0, 0);
  for (int kt = 0; kt < nk; ++kt){
    __syncthreads();
    if (kt + 1 < nk) stage((kt + 1) & 1, kt + 1);
    const int bufi = kt & 1;
    s16x8 af[4], bfr[4];
#pragma unroll
    for (int i = 0; i < 4; i++){
      af[i]  = *(const s16x8*)&Al[bufi][(wm + i*16 + lr) * BK + lg * 8];
      bfr[i] = *(const s16x8*)&Bl[bufi][(wn + i*16 + lr) * BK + lg * 8];
    }
#pragma unroll
    for (int i = 0; i < 4; i++)
#pragma unroll
      for (int j = 0; j < 4; j++)
        acc[i][j] = __builtin_amdgcn_mfma_f32_16x16x32_bf16(af[i], bfr[j], acc[i][j], 0, 0, 0);
  }

#pragma unroll
  for (int fm = 0; fm < 4; fm++){
    const int gmb = m0 + wm + fm * 16 + lg * 4;
#pragma unroll
    for (int fn = 0; fn < 4; fn++){
      const int gn = n0 + wn + fn * 16 + lr;
#pragma unroll
      for (int i = 0; i < 4; i++){
        const int gm = gmb + i;
        float v = acc[fm][fn][i];
        if (MODE == 0){
          const int cls = gn >> 10, nn = gn & 1023;
          if (cls == 0)      ((u16*)o0)[(size_t)gm * D_EMB + nn] = f2bf(v + bias0[nn]);
          else if (cls == 1) ((u16*)o1)[(size_t)gm * D_EMB + nn] = f2bf(v + bias1[nn]);
          else {
            const int hh = nn >> 6, ss = nn & 63, bb = gm >> 10, tt = gm & 1023;
            ((u16*)o2)[(((size_t)(bb * NH + hh)) * HS + ss) * NSEQ + tt] = f2bf(v + bias2[nn]);
          }
        } else if (MODE == 1){
          ((float*)o0)[(size_t)gm * N + gn] = resid[(size_t)gm * N + gn] + v + bias0[gn];
        } else {
          float y = v + bias0[gn];
          y = y > 0.f ? y : 0.01f * y;
          ((u16*)o0)[(size_t)gm * N + gn] = f2bf(y);
        }
      }
    }
  }
}

// ---------------- flash attention (round-3, unchanged) ----------------
__global__ __launch_bounds__(256) void attn_kernel(
    const u16* __restrict__ Qb, const u16* __restrict__ Kb, const u16* __restrict__ VT,
    u16* __restrict__ attnC)
{
  const int bid = blockIdx.x;
  const int bh = bid & 127, qt = bid >> 7;
  const int b = bh >> 4, h = bh & 15;
  const int tid = threadIdx.x, w = tid >> 6, lane = tid & 63;
  const int lr = lane & 15, lg = lane >> 4;
  const int q0 = qt * 128 + w * 32;

  __shared__ alignas(16) u16 Kl[2][64*64];
  __shared__ alignas(16) u16 Vl[2][64*64];
  __shared__ alignas(16) u16 Pl[4][32][72];

  const int srow = tid >> 3, scg = tid & 7;
  const u16* kbase = Kb + (size_t)(b * NSEQ) * D_EMB + h * HS;
  const u16* vbase = VT + ((size_t)(b * NH + h)) * HS * NSEQ;

  auto stage = [&](int buf, int kt){
    const int tk = kt * 64;
#pragma unroll
    for (int p = 0; p < 2; ++p){
      const int row = srow + p * 32;
      const int sc = scg ^ (row & 7);
      gload_lds16(kbase + (size_t)(tk + row) * D_EMB + sc * 8, &Kl[buf][(p * 256 + tid) * 8]);
      gload_lds16(vbase + (size_t)row * NSEQ + tk + sc * 8,    &Vl[buf][(p * 256 + tid) * 8]);
    }
  };

  s16x8 aq[2][2];
#pragma unroll
  for (int rb = 0; rb < 2; rb++)
#pragma unroll
    for (int kh = 0; kh < 2; kh++)
      aq[rb][kh] = *(const s16x8*)(Qb + (size_t)(b * NSEQ + q0 + rb * 16 + lr) * D_EMB
                                   + h * HS + kh * 32 + lg * 8);

  float m_i[2][4], l_i[2][4];
  f32x4 zero = {0.f, 0.f, 0.f, 0.f};
  f32x4 ao[2][4];
#pragma unroll
  for (int rb = 0; rb < 2; rb++)
#pragma unroll
    for (int i = 0; i < 4; i++){ m_i[rb][i] = -1e30f; l_i[rb][i] = 0.f; ao[rb][i] = zero; }

  const float scale = 0.125f;
  const int rsw = lr & 7;

  stage(0, 0);
  for (int kt = 0; kt < NSEQ / 64; ++kt){
    __syncthreads();
    if (kt + 1 < NSEQ / 64) stage((kt + 1) & 1, kt + 1);
    const int cur = kt & 1;

    f32x4 sv[2][4];
#pragma unroll
    for (int rb = 0; rb < 2; rb++)
#pragma unroll
      for (int fn = 0; fn < 4; fn++) sv[rb][fn] = zero;
#pragma unroll
    for (int fn = 0; fn < 4; fn++){
      const int krow = fn * 16 + lr;
#pragma unroll
      for (int kh = 0; kh < 2; kh++){
        const int chunk = (kh * 4 + lg) ^ rsw;
        s16x8 kf = *(const s16x8*)&Kl[cur][krow * 64 + chunk * 8];
        sv[0][fn] = __builtin_amdgcn_mfma_f32_16x16x32_bf16(aq[0][kh], kf, sv[0][fn], 0, 0, 0);
        sv[1][fn] = __builtin_amdgcn_mfma_f32_16x16x32_bf16(aq[1][kh], kf, sv[1][fn], 0, 0, 0);
      }
    }

#pragma unroll
    for (int rb = 0; rb < 2; rb++){
      float p[4][4];
#pragma unroll
      for (int i = 0; i < 4; i++){
        float s0 = sv[rb][0][i] * scale, s1 = sv[rb][1][i] * scale;
        float s2 = sv[rb][2][i] * scale, s3 = sv[rb][3][i] * scale;
        float rmax = fmaxf(fmaxf(s0, s1), fmaxf(s2, s3));
#pragma unroll
        for (int mm = 8; mm > 0; mm >>= 1) rmax = fmaxf(rmax, __shfl_xor(rmax, mm));
        float mnew = fmaxf(m_i[rb][i], rmax);
        float fac = __expf(m_i[rb][i] - mnew);
        float p0 = __expf(s0 - mnew), p1 = __expf(s1 - mnew);
        float p2 = __expf(s2 - mnew), p3 = __expf(s3 - mnew);
        p[0][i] = p0; p[1][i] = p1; p[2][i] = p2; p[3][i] = p3;
        float rs = (p0 + p1) + (p2 + p3);
#pragma unroll
        for (int mm = 8; mm > 0; mm >>= 1) rs += __shfl_xor(rs, mm);
        l_i[rb][i] = l_i[rb][i] * fac + rs;
        m_i[rb][i] = mnew;
#pragma unroll
        for (int fn = 0; fn < 4; fn++) ao[rb][fn][i] *= fac;
      }
#pragma unroll
      for (int fn = 0; fn < 4; fn++)
#pragma unroll
        for (int i = 0; i < 4; i++)
          Pl[w][rb * 16 + lg * 4 + i][fn * 16 + lr] = f2bf(p[fn][i]);
    }

    s16x8 vf[4][2];
#pragma unroll
    for (int fn = 0; fn < 4; fn++){
      const int vrow = fn * 16 + lr;
#pragma unroll
      for (int kh = 0; kh < 2; kh++){
        const int chunk = (kh * 4 + lg) ^ rsw;
        vf[fn][kh] = *(const s16x8*)&Vl[cur][vrow * 64 + chunk * 8];
      }
    }
#pragma unroll
    for (int rb = 0; rb < 2; rb++){
      s16x8 pa0 = *(const s16x8*)&Pl[w][rb * 16 + lr][lg * 8];
      s16x8 pa1 = *(const s16x8*)&Pl[w][rb * 16 + lr][32 + lg * 8];
#pragma unroll
      for (int fn = 0; fn < 4; fn++){
        ao[rb][fn] = __builtin_amdgcn_mfma_f32_16x16x32_bf16(pa0, vf[fn][0], ao[rb][fn], 0, 0, 0);
        ao[rb][fn] = __builtin_amdgcn_mfma_f32_16x16x32_bf16(pa1, vf[fn][1], ao[rb][fn], 0, 0, 0);
      }
    }
  }

#pragma unroll
  for (int rb = 0; rb < 2; rb++)
#pragma unroll
    for (int fn = 0; fn < 4; fn++)
#pragma unroll
      for (int i = 0; i < 4; i++){
        float v = ao[rb][fn][i] / l_i[rb][i];
        attnC[(size_t)(b * NSEQ + q0 + rb * 16 + lg * 4 + i) * D_EMB + h * HS + fn * 16 + lr] = f2bf(v);
      }
}

// ---------------- host ----------------
extern "C" void kernel_launch(void* const* d_in, const int* in_sizes, int n_in,
                              void* d_out, int out_size, void* d_ws, size_t ws_size,
                              hipStream_t stream)
{
  const float* x    = (const float*)d_in[0];
  const float* Wq   = (const float*)d_in[1];
  const float* bq   = (const float*)d_in[2];
  const float* Wk   = (const float*)d_in[3];
  const float* bk   = (const float*)d_in[4];
  const float* Wv   = (const float*)d_in[5];
  const float* bv   = (const float*)d_in[6];
  const float* Wp   = (const float*)d_in[7];
  const float* bp   = (const float*)d_in[8];
  const float* W1   = (const float*)d_in[9];
  const float* b1   = (const float*)d_in[10];
  const float* W2   = (const float*)d_in[11];
  const float* b2   = (const float*)d_in[12];
  const float* ln1g = (const float*)d_in[13];
  const float* ln1b = (const float*)d_in[14];
  const float* ln2g = (const float*)d_in[15];
  const float* ln2b = (const float*)d_in[16];
  float* out = (float*)d_out;

  char* ws = (char*)d_ws;
  size_t off = 0;
  auto mk = [&](size_t bytes)->void*{ void* p = ws + off; off += (bytes + 255) & ~(size_t)255; return p; };
  u16*  h1    = (u16*) mk((size_t)MTOT * D_EMB * 2);
  u16*  Qb    = (u16*) mk((size_t)MTOT * D_EMB * 2);
  u16*  Kb    = (u16*) mk((size_t)MTOT * D_EMB * 2);
  u16*  VTb   = (u16*) mk((size_t)MTOT * D_EMB * 2);
  u16*  attnC = (u16*) mk((size_t)MTOT * D_EMB * 2);
  float* x1   = (float*)mk((size_t)MTOT * D_EMB * 4);
  u16*  h2    = (u16*) mk((size_t)MTOT * D_EMB * 2);
  u16*  ffb   = (u16*) mk((size_t)MTOT * DFF * 2);
  u16*  WqkvT = (u16*) mk((size_t)3 * D_EMB * D_EMB * 2);
  u16*  WpT   = (u16*) mk((size_t)D_EMB * D_EMB * 2);
  u16*  W1T   = (u16*) mk((size_t)D_EMB * DFF * 2);
  u16*  W2T   = (u16*) mk((size_t)D_EMB * DFF * 2);

  dim3 tb(32, 8, 1);
  transpose_cvt<<<dim3(HS/32, D_EMB/32, NH), tb, 0, stream>>>(Wq, WqkvT,                         D_EMB, HS, (size_t)D_EMB*HS, (size_t)HS*D_EMB);
  transpose_cvt<<<dim3(HS/32, D_EMB/32, NH), tb, 0, stream>>>(Wk, WqkvT + (size_t)D_EMB*D_EMB,   D_EMB, HS, (size_t)D_EMB*HS, (size_t)HS*D_EMB);
  transpose_cvt<<<dim3(HS/32, D_EMB/32, NH), tb, 0, stream>>>(Wv, WqkvT + (size_t)2*D_EMB*D_EMB, D_EMB, HS, (size_t)D_EMB*HS, (size_t)HS*D_EMB);
  transpose_cvt<<<dim3(D_EMB/32, D_EMB/32, 1), tb, 0, stream>>>(Wp, WpT,  D_EMB, D_EMB, 0, 0);
  transpose_cvt<<<dim3(DFF/32,  D_EMB/32, 1), tb, 0, stream>>>(W1, W1T,  D_EMB, DFF,   0, 0);
  transpose_cvt<<<dim3(D_EMB/32, DFF/32,  1), tb, 0, stream>>>(W2, W2T,  DFF,   D_EMB, 0, 0);

  ln_kernel<<<MTOT, 256, 0, stream>>>(x, ln1g, ln1b, h1);

  // opt-in to >64KB dynamic LDS; fall back to proven 128^2 GEMM on failure
  bool big = true;
  big &= hipFuncSetAttribute(reinterpret_cast<const void*>(&gemm256<0,256>),
                             hipFuncAttributeMaxDynamicSharedMemorySize, 131072) == hipSuccess;
  big &= hipFuncSetAttribute(reinterpret_cast<const void*>(&gemm256<2,256>),
                             hipFuncAttributeMaxDynamicSharedMemorySize, 131072) == hipSuccess;
  big &= hipFuncSetAttribute(reinterpret_cast<const void*>(&gemm256<1,128>),
                             hipFuncAttributeMaxDynamicSharedMemorySize, 98304) == hipSuccess;

  if (big){
    gemm256<0,256><<<dim3(MTOT/256, 3*D_EMB/256), 512, 131072, stream>>>(h1, WqkvT, MTOT, 3*D_EMB, D_EMB,
        bq, bk, bv, nullptr, Qb, Kb, VTb);
    attn_kernel<<<NB*NH*(NSEQ/128), 256, 0, stream>>>(Qb, Kb, VTb, attnC);
    gemm256<1,128><<<dim3(MTOT/256, D_EMB/128), 512, 98304, stream>>>(attnC, WpT, MTOT, D_EMB, D_EMB,
        bp, nullptr, nullptr, x, x1, nullptr, nullptr);
    ln_kernel<<<MTOT, 256, 0, stream>>>(x1, ln2g, ln2b, h2);
    gemm256<2,256><<<dim3(MTOT/256, DFF/256), 512, 131072, stream>>>(h2, W1T, MTOT, DFF, D_EMB,
        b1, nullptr, nullptr, nullptr, ffb, nullptr, nullptr);
    gemm256<1,128><<<dim3(MTOT/256, D_EMB/128), 512, 98304, stream>>>(ffb, W2T, MTOT, D_EMB, DFF,
        b2, nullptr, nullptr, x1, out, nullptr, nullptr);
  } else {
    gemm_bt<0><<<dim3(MTOT/BM, (3*D_EMB)/BN), 256, 0, stream>>>(h1, WqkvT, MTOT, 3*D_EMB, D_EMB,
        bq, bk, bv, nullptr, Qb, Kb, VTb);
    attn_kernel<<<NB*NH*(NSEQ/128), 256, 0, stream>>>(Qb, Kb, VTb, attnC);
    gemm_bt<1><<<dim3(MTOT/BM, D_EMB/BN), 256, 0, stream>>>(attnC, WpT, MTOT, D_EMB, D_EMB,
        bp, nullptr, nullptr, x, x1, nullptr, nullptr);
    ln_kernel<<<MTOT, 256, 0, stream>>>(x1, ln2g, ln2b, h2);
    gemm_bt<2><<<dim3(MTOT/BM, DFF/BN), 256, 0, stream>>>(h2, W1T, MTOT, DFF, D_EMB,
        b1, nullptr, nullptr, nullptr, ffb, nullptr, nullptr);
    gemm_bt<1><<<dim3(MTOT/BM, D_EMB/BN), 256, 0, stream>>>(ffb, W2T, MTOT, D_EMB, DFF,
        b2, nullptr, nullptr, x1, out, nullptr, nullptr);
  }
}

// Round 9
// 485.985 us; speedup vs baseline: 1.0389x; 1.0229x over previous
//
#include <hip/hip_runtime.h>
#include <cstdint>
#include <cstddef>

typedef unsigned short u16;
typedef __attribute__((ext_vector_type(4))) float f32x4;
typedef __attribute__((ext_vector_type(8))) short s16x8;

#define D_EMB 1024
#define NSEQ 1024
#define NB 8
#define NH 16
#define HS 64
#define DFF 4096
#define MTOT (NB*NSEQ)

__device__ __forceinline__ u16 f2bf(float f){
  unsigned u = __float_as_uint(f);
  u += 0x7FFFu + ((u >> 16) & 1u);     // round-to-nearest-even
  return (u16)(u >> 16);
}

__device__ __forceinline__ void gload_lds16(const void* g, void* l){
  __builtin_amdgcn_global_load_lds((const __attribute__((address_space(1))) void*)g,
                                   (__attribute__((address_space(3))) void*)l, 16, 0, 0);
}

// ---------------- tiled transpose + fp32->bf16 convert ----------------
__global__ void transpose_cvt(const float* __restrict__ in, u16* __restrict__ out,
                              int R, int C, size_t inStride, size_t outStride){
  __shared__ float t[32][33];
  const float* ip = in + (size_t)blockIdx.z * inStride;
  u16* op = out + (size_t)blockIdx.z * outStride;
  int c0 = blockIdx.x * 32, r0 = blockIdx.y * 32;
  int tx = threadIdx.x, ty = threadIdx.y;
#pragma unroll
  for (int j = 0; j < 32; j += 8)
    t[ty + j][tx] = ip[(size_t)(r0 + ty + j) * C + (c0 + tx)];
  __syncthreads();
#pragma unroll
  for (int j = 0; j < 32; j += 8)
    op[(size_t)(c0 + ty + j) * R + (r0 + tx)] = f2bf(t[tx][ty + j]);
}

// ---------------- LayerNorm (fp32 in, bf16 out) ----------------
__global__ __launch_bounds__(256) void ln_kernel(const float* __restrict__ x,
    const float* __restrict__ g, const float* __restrict__ bb, u16* __restrict__ out){
  int row = blockIdx.x;
  const float* xr = x + (size_t)row * D_EMB;
  int c = threadIdx.x * 4;
  f32x4 v = *(const f32x4*)(xr + c);
  float s1 = v[0] + v[1] + v[2] + v[3];
  float s2 = v[0]*v[0] + v[1]*v[1] + v[2]*v[2] + v[3]*v[3];
#pragma unroll
  for (int m = 32; m > 0; m >>= 1){ s1 += __shfl_xor(s1, m); s2 += __shfl_xor(s2, m); }
  __shared__ float ps1[4], ps2[4];
  int w = threadIdx.x >> 6;
  if ((threadIdx.x & 63) == 0){ ps1[w] = s1; ps2[w] = s2; }
  __syncthreads();
  s1 = ps1[0] + ps1[1] + ps1[2] + ps1[3];
  s2 = ps2[0] + ps2[1] + ps2[2] + ps2[3];
  float mu = s1 * (1.f / D_EMB);
  float var = s2 * (1.f / D_EMB) - mu * mu;
  float rs = rsqrtf(var + 1e-5f);
  ushort4 o;
  o.x = f2bf((v[0]-mu)*rs*g[c+0] + bb[c+0]);
  o.y = f2bf((v[1]-mu)*rs*g[c+1] + bb[c+1]);
  o.z = f2bf((v[2]-mu)*rs*g[c+2] + bb[c+2]);
  o.w = f2bf((v[3]-mu)*rs*g[c+3] + bb[c+3]);
  *(ushort4*)(out + (size_t)row * D_EMB + c) = o;
}

// ======== 2-phase GEMM template (r3 structure, traffic-aware shapes) ========
// C = A[M,K] * Bt[N,K]^T, bf16 in, fp32 acc. BK=32, double-buffered LDS,
// __syncthreads-scheduled (compiler emits counted lgkm/vm waits; implicit
// wave-level overlap via 2+ blocks/CU does the pipelining - m114).
// Swizzle (proven 0-conflict in r7): read chunk ch=(lg+(row>>1))&3, staged
// from inverse-permuted global chunk; LDS layout stays linear.
// Geometry: wave tile 64x64; WCN=BNT/64 waves across N, NWAVE/WCN down M.
template<int MODE, int BMT, int BNT, int NTHR>
__global__ __launch_bounds__(NTHR) void gemm2ph(
    const u16* __restrict__ A, const u16* __restrict__ Bt,
    int M, int N, int K,
    const float* __restrict__ bias0, const float* __restrict__ bias1,
    const float* __restrict__ bias2, const float* __restrict__ resid,
    void* __restrict__ o0, void* __restrict__ o1, void* __restrict__ o2)
{
  constexpr int NWAVE = NTHR/64;
  constexpr int WCN = BNT/64, WRN = NWAVE/WCN;
  static_assert(BMT/WRN == 64, "wave tile is 64x64");
  constexpr int RPP = NTHR/4;                    // rows staged per pass
  constexpr int ALD = (BMT*32)/(NTHR*8);         // 16B loads/thread for A
  constexpr int BLD = (BNT*32)/(NTHR*8);
  __shared__ alignas(16) u16 Al[2][BMT*32];
  __shared__ alignas(16) u16 Bl[2][BNT*32];

  const int tid = threadIdx.x;
  const int wid = tid>>6, lane = tid&63, lr = lane&15, lg = lane>>4;
  const int wr = wid/WCN, wc = wid%WCN;

  // XCD swizzle (all grids divisible by 8)
  const int gx = gridDim.x;
  const int nwg = gx * gridDim.y;
  const int bid = blockIdx.x + blockIdx.y*gx;
  const int wg = (bid&7)*(nwg>>3) + (bid>>3);
  const int m0 = (wg % gx) * BMT;
  const int n0 = (wg / gx) * BNT;

  const int srow = tid>>2;                                   // staging row
  const int scs = (((tid&3) - ((srow>>1)&3)) & 3) * 8;       // inv-swizzled src chunk

  auto stage = [&](int buf, int kt){
    const u16* asrc = A + (size_t)(m0 + srow)*K + kt*32 + scs;
#pragma unroll
    for (int r = 0; r < ALD; ++r)
      gload_lds16(asrc + (size_t)(r*RPP)*K, &Al[buf][r*(NTHR*8) + tid*8]);
    const u16* bsrc = Bt + (size_t)(n0 + srow)*K + kt*32 + scs;
#pragma unroll
    for (int r = 0; r < BLD; ++r)
      gload_lds16(bsrc + (size_t)(r*RPP)*K, &Bl[buf][r*(NTHR*8) + tid*8]);
  };

  f32x4 acc[4][4];
#pragma unroll
  for (int i = 0; i < 4; i++)
#pragma unroll
    for (int j = 0; j < 4; j++) acc[i][j] = {0.f,0.f,0.f,0.f};

  const int nk = K/32;
  stage(0, 0);
  for (int kt = 0; kt < nk; ++kt){
    __syncthreads();                   // drains vmcnt: stage(kt) visible
    if (kt + 1 < nk) stage((kt+1)&1, kt+1);
    const int buf = kt & 1;
    s16x8 af[4], bf[4];
#pragma unroll
    for (int i = 0; i < 4; i++){
      const int ar = wr*64 + i*16 + lr;
      af[i] = *(const s16x8*)&Al[buf][ar*32 + (((lg + (ar>>1)) & 3)<<3)];
      const int br = wc*64 + i*16 + lr;
      bf[i] = *(const s16x8*)&Bl[buf][br*32 + (((lg + (br>>1)) & 3)<<3)];
    }
#pragma unroll
    for (int i = 0; i < 4; i++)
#pragma unroll
      for (int j = 0; j < 4; j++)
        acc[i][j] = __builtin_amdgcn_mfma_f32_16x16x32_bf16(af[i], bf[j], acc[i][j], 0, 0, 0);
  }

  // epilogue: lane holds C[row=lg*4+i][col=lr] per 16x16 fragment
#pragma unroll
  for (int fm = 0; fm < 4; fm++){
    const int gmb = m0 + wr*64 + fm*16 + lg*4;
#pragma unroll
    for (int fn = 0; fn < 4; fn++){
      const int gn = n0 + wc*64 + fn*16 + lr;
#pragma unroll
      for (int i = 0; i < 4; i++){
        const int gm = gmb + i;
        float v = acc[fm][fn][i];
        if (MODE == 0){
          const int cls = gn >> 10, nn = gn & 1023;
          if (cls == 0)      ((u16*)o0)[(size_t)gm * D_EMB + nn] = f2bf(v + bias0[nn]);
          else if (cls == 1) ((u16*)o1)[(size_t)gm * D_EMB + nn] = f2bf(v + bias1[nn]);
          else {
            const int hh = nn >> 6, ss = nn & 63, bb = gm >> 10, tt = gm & 1023;
            ((u16*)o2)[(((size_t)(bb * NH + hh)) * HS + ss) * NSEQ + tt] = f2bf(v + bias2[nn]);
          }
        } else if (MODE == 1){
          ((float*)o0)[(size_t)gm * N + gn] = resid[(size_t)gm * N + gn] + v + bias0[gn];
        } else {
          float y = v + bias0[gn];
          y = y > 0.f ? y : 0.01f * y;
          ((u16*)o0)[(size_t)gm * N + gn] = f2bf(y);
        }
      }
    }
  }
}

// ---------------- flash attention (round-3, unchanged) ----------------
__global__ __launch_bounds__(256) void attn_kernel(
    const u16* __restrict__ Qb, const u16* __restrict__ Kb, const u16* __restrict__ VT,
    u16* __restrict__ attnC)
{
  const int bid = blockIdx.x;
  const int bh = bid & 127, qt = bid >> 7;
  const int b = bh >> 4, h = bh & 15;
  const int tid = threadIdx.x, w = tid >> 6, lane = tid & 63;
  const int lr = lane & 15, lg = lane >> 4;
  const int q0 = qt * 128 + w * 32;

  __shared__ alignas(16) u16 Kl[2][64*64];
  __shared__ alignas(16) u16 Vl[2][64*64];
  __shared__ alignas(16) u16 Pl[4][32][72];

  const int srow = tid >> 3, scg = tid & 7;
  const u16* kbase = Kb + (size_t)(b * NSEQ) * D_EMB + h * HS;
  const u16* vbase = VT + ((size_t)(b * NH + h)) * HS * NSEQ;

  auto stage = [&](int buf, int kt){
    const int tk = kt * 64;
#pragma unroll
    for (int p = 0; p < 2; ++p){
      const int row = srow + p * 32;
      const int sc = scg ^ (row & 7);
      gload_lds16(kbase + (size_t)(tk + row) * D_EMB + sc * 8, &Kl[buf][(p * 256 + tid) * 8]);
      gload_lds16(vbase + (size_t)row * NSEQ + tk + sc * 8,    &Vl[buf][(p * 256 + tid) * 8]);
    }
  };

  s16x8 aq[2][2];
#pragma unroll
  for (int rb = 0; rb < 2; rb++)
#pragma unroll
    for (int kh = 0; kh < 2; kh++)
      aq[rb][kh] = *(const s16x8*)(Qb + (size_t)(b * NSEQ + q0 + rb * 16 + lr) * D_EMB
                                   + h * HS + kh * 32 + lg * 8);

  float m_i[2][4], l_i[2][4];
  f32x4 zero = {0.f, 0.f, 0.f, 0.f};
  f32x4 ao[2][4];
#pragma unroll
  for (int rb = 0; rb < 2; rb++)
#pragma unroll
    for (int i = 0; i < 4; i++){ m_i[rb][i] = -1e30f; l_i[rb][i] = 0.f; ao[rb][i] = zero; }

  const float scale = 0.125f;
  const int rsw = lr & 7;

  stage(0, 0);
  for (int kt = 0; kt < NSEQ / 64; ++kt){
    __syncthreads();
    if (kt + 1 < NSEQ / 64) stage((kt + 1) & 1, kt + 1);
    const int cur = kt & 1;

    f32x4 sv[2][4];
#pragma unroll
    for (int rb = 0; rb < 2; rb++)
#pragma unroll
      for (int fn = 0; fn < 4; fn++) sv[rb][fn] = zero;
#pragma unroll
    for (int fn = 0; fn < 4; fn++){
      const int krow = fn * 16 + lr;
#pragma unroll
      for (int kh = 0; kh < 2; kh++){
        const int chunk = (kh * 4 + lg) ^ rsw;
        s16x8 kf = *(const s16x8*)&Kl[cur][krow * 64 + chunk * 8];
        sv[0][fn] = __builtin_amdgcn_mfma_f32_16x16x32_bf16(aq[0][kh], kf, sv[0][fn], 0, 0, 0);
        sv[1][fn] = __builtin_amdgcn_mfma_f32_16x16x32_bf16(aq[1][kh], kf, sv[1][fn], 0, 0, 0);
      }
    }

#pragma unroll
    for (int rb = 0; rb < 2; rb++){
      float p[4][4];
#pragma unroll
      for (int i = 0; i < 4; i++){
        float s0 = sv[rb][0][i] * scale, s1 = sv[rb][1][i] * scale;
        float s2 = sv[rb][2][i] * scale, s3 = sv[rb][3][i] * scale;
        float rmax = fmaxf(fmaxf(s0, s1), fmaxf(s2, s3));
#pragma unroll
        for (int mm = 8; mm > 0; mm >>= 1) rmax = fmaxf(rmax, __shfl_xor(rmax, mm));
        float mnew = fmaxf(m_i[rb][i], rmax);
        float fac = __expf(m_i[rb][i] - mnew);
        float p0 = __expf(s0 - mnew), p1 = __expf(s1 - mnew);
        float p2 = __expf(s2 - mnew), p3 = __expf(s3 - mnew);
        p[0][i] = p0; p[1][i] = p1; p[2][i] = p2; p[3][i] = p3;
        float rs = (p0 + p1) + (p2 + p3);
#pragma unroll
        for (int mm = 8; mm > 0; mm >>= 1) rs += __shfl_xor(rs, mm);
        l_i[rb][i] = l_i[rb][i] * fac + rs;
        m_i[rb][i] = mnew;
#pragma unroll
        for (int fn = 0; fn < 4; fn++) ao[rb][fn][i] *= fac;
      }
#pragma unroll
      for (int fn = 0; fn < 4; fn++)
#pragma unroll
        for (int i = 0; i < 4; i++)
          Pl[w][rb * 16 + lg * 4 + i][fn * 16 + lr] = f2bf(p[fn][i]);
    }

    s16x8 vf[4][2];
#pragma unroll
    for (int fn = 0; fn < 4; fn++){
      const int vrow = fn * 16 + lr;
#pragma unroll
      for (int kh = 0; kh < 2; kh++){
        const int chunk = (kh * 4 + lg) ^ rsw;
        vf[fn][kh] = *(const s16x8*)&Vl[cur][vrow * 64 + chunk * 8];
      }
    }
#pragma unroll
    for (int rb = 0; rb < 2; rb++){
      s16x8 pa0 = *(const s16x8*)&Pl[w][rb * 16 + lr][lg * 8];
      s16x8 pa1 = *(const s16x8*)&Pl[w][rb * 16 + lr][32 + lg * 8];
#pragma unroll
      for (int fn = 0; fn < 4; fn++){
        ao[rb][fn] = __builtin_amdgcn_mfma_f32_16x16x32_bf16(pa0, vf[fn][0], ao[rb][fn], 0, 0, 0);
        ao[rb][fn] = __builtin_amdgcn_mfma_f32_16x16x32_bf16(pa1, vf[fn][1], ao[rb][fn], 0, 0, 0);
      }
    }
  }

#pragma unroll
  for (int rb = 0; rb < 2; rb++)
#pragma unroll
    for (int fn = 0; fn < 4; fn++)
#pragma unroll
      for (int i = 0; i < 4; i++){
        float v = ao[rb][fn][i] / l_i[rb][i];
        attnC[(size_t)(b * NSEQ + q0 + rb * 16 + lg * 4 + i) * D_EMB + h * HS + fn * 16 + lr] = f2bf(v);
      }
}

// ---------------- host ----------------
extern "C" void kernel_launch(void* const* d_in, const int* in_sizes, int n_in,
                              void* d_out, int out_size, void* d_ws, size_t ws_size,
                              hipStream_t stream)
{
  const float* x    = (const float*)d_in[0];
  const float* Wq   = (const float*)d_in[1];
  const float* bq   = (const float*)d_in[2];
  const float* Wk   = (const float*)d_in[3];
  const float* bk   = (const float*)d_in[4];
  const float* Wv   = (const float*)d_in[5];
  const float* bv   = (const float*)d_in[6];
  const float* Wp   = (const float*)d_in[7];
  const float* bp   = (const float*)d_in[8];
  const float* W1   = (const float*)d_in[9];
  const float* b1   = (const float*)d_in[10];
  const float* W2   = (const float*)d_in[11];
  const float* b2   = (const float*)d_in[12];
  const float* ln1g = (const float*)d_in[13];
  const float* ln1b = (const float*)d_in[14];
  const float* ln2g = (const float*)d_in[15];
  const float* ln2b = (const float*)d_in[16];
  float* out = (float*)d_out;

  char* ws = (char*)d_ws;
  size_t off = 0;
  auto mk = [&](size_t bytes)->void*{ void* p = ws + off; off += (bytes + 255) & ~(size_t)255; return p; };
  u16*  h1    = (u16*) mk((size_t)MTOT * D_EMB * 2);
  u16*  Qb    = (u16*) mk((size_t)MTOT * D_EMB * 2);
  u16*  Kb    = (u16*) mk((size_t)MTOT * D_EMB * 2);
  u16*  VTb   = (u16*) mk((size_t)MTOT * D_EMB * 2);
  u16*  attnC = (u16*) mk((size_t)MTOT * D_EMB * 2);
  float* x1   = (float*)mk((size_t)MTOT * D_EMB * 4);
  u16*  h2    = (u16*) mk((size_t)MTOT * D_EMB * 2);
  u16*  ffb   = (u16*) mk((size_t)MTOT * DFF * 2);
  u16*  WqkvT = (u16*) mk((size_t)3 * D_EMB * D_EMB * 2);
  u16*  WpT   = (u16*) mk((size_t)D_EMB * D_EMB * 2);
  u16*  W1T   = (u16*) mk((size_t)D_EMB * DFF * 2);
  u16*  W2T   = (u16*) mk((size_t)D_EMB * DFF * 2);

  dim3 tb(32, 8, 1);
  transpose_cvt<<<dim3(HS/32, D_EMB/32, NH), tb, 0, stream>>>(Wq, WqkvT,                         D_EMB, HS, (size_t)D_EMB*HS, (size_t)HS*D_EMB);
  transpose_cvt<<<dim3(HS/32, D_EMB/32, NH), tb, 0, stream>>>(Wk, WqkvT + (size_t)D_EMB*D_EMB,   D_EMB, HS, (size_t)D_EMB*HS, (size_t)HS*D_EMB);
  transpose_cvt<<<dim3(HS/32, D_EMB/32, NH), tb, 0, stream>>>(Wv, WqkvT + (size_t)2*D_EMB*D_EMB, D_EMB, HS, (size_t)D_EMB*HS, (size_t)HS*D_EMB);
  transpose_cvt<<<dim3(D_EMB/32, D_EMB/32, 1), tb, 0, stream>>>(Wp, WpT,  D_EMB, D_EMB, 0, 0);
  transpose_cvt<<<dim3(DFF/32,  D_EMB/32, 1), tb, 0, stream>>>(W1, W1T,  D_EMB, DFF,   0, 0);
  transpose_cvt<<<dim3(D_EMB/32, DFF/32,  1), tb, 0, stream>>>(W2, W2T,  DFF,   D_EMB, 0, 0);

  ln_kernel<<<MTOT, 256, 0, stream>>>(x, ln1g, ln1b, h1);

  // QKV: M=8192, N=3072, K=1024 — fat-N 128x256, 512 thr, grid 64x12=768
  gemm2ph<0,128,256,512><<<dim3(MTOT/128, 3*D_EMB/256), 512, 0, stream>>>(
      h1, WqkvT, MTOT, 3*D_EMB, D_EMB, bq, bk, bv, nullptr, Qb, Kb, VTb);

  attn_kernel<<<NB*NH*(NSEQ/128), 256, 0, stream>>>(Qb, Kb, VTb, attnC);

  // proj: M=8192, N=1024, K=1024 — 64x256, 256 thr, grid 128x4=512
  gemm2ph<1,64,256,256><<<dim3(MTOT/64, D_EMB/256), 256, 0, stream>>>(
      attnC, WpT, MTOT, D_EMB, D_EMB, bp, nullptr, nullptr, x, x1, nullptr, nullptr);

  ln_kernel<<<MTOT, 256, 0, stream>>>(x1, ln2g, ln2b, h2);

  // FF1: M=8192, N=4096, K=1024 — 128x256, grid 64x16=1024
  gemm2ph<2,128,256,512><<<dim3(MTOT/128, DFF/256), 512, 0, stream>>>(
      h2, W1T, MTOT, DFF, D_EMB, b1, nullptr, nullptr, nullptr, ffb, nullptr, nullptr);

  // FF2: M=8192, N=1024, K=4096 — 64x256, grid 128x4=512
  gemm2ph<1,64,256,256><<<dim3(MTOT/64, D_EMB/256), 256, 0, stream>>>(
      ffb, W2T, MTOT, D_EMB, DFF, b2, nullptr, nullptr, x1, out, nullptr, nullptr);
}

// Round 10
// 467.209 us; speedup vs baseline: 1.0806x; 1.0402x over previous
//
#include <hip/hip_runtime.h>
#include <cstdint>
#include <cstddef>

typedef unsigned short u16;
typedef __attribute__((ext_vector_type(4))) float f32x4;
typedef __attribute__((ext_vector_type(8))) short s16x8;

#define D_EMB 1024
#define NSEQ 1024
#define NB 8
#define NH 16
#define HS 64
#define DFF 4096
#define MTOT (NB*NSEQ)

__device__ __forceinline__ u16 f2bf(float f){
  unsigned u = __float_as_uint(f);
  u += 0x7FFFu + ((u >> 16) & 1u);     // round-to-nearest-even
  return (u16)(u >> 16);
}

__device__ __forceinline__ void gload_lds16(const void* g, void* l){
  __builtin_amdgcn_global_load_lds((const __attribute__((address_space(1))) void*)g,
                                   (__attribute__((address_space(3))) void*)l, 16, 0, 0);
}

// ---------------- tiled transpose + fp32->bf16 convert ----------------
__global__ void transpose_cvt(const float* __restrict__ in, u16* __restrict__ out,
                              int R, int C, size_t inStride, size_t outStride){
  __shared__ float t[32][33];
  const float* ip = in + (size_t)blockIdx.z * inStride;
  u16* op = out + (size_t)blockIdx.z * outStride;
  int c0 = blockIdx.x * 32, r0 = blockIdx.y * 32;
  int tx = threadIdx.x, ty = threadIdx.y;
#pragma unroll
  for (int j = 0; j < 32; j += 8)
    t[ty + j][tx] = ip[(size_t)(r0 + ty + j) * C + (c0 + tx)];
  __syncthreads();
#pragma unroll
  for (int j = 0; j < 32; j += 8)
    op[(size_t)(c0 + ty + j) * R + (r0 + tx)] = f2bf(t[tx][ty + j]);
}

// ---------------- LayerNorm (fp32 in, bf16 out) ----------------
__global__ __launch_bounds__(256) void ln_kernel(const float* __restrict__ x,
    const float* __restrict__ g, const float* __restrict__ bb, u16* __restrict__ out){
  int row = blockIdx.x;
  const float* xr = x + (size_t)row * D_EMB;
  int c = threadIdx.x * 4;
  f32x4 v = *(const f32x4*)(xr + c);
  float s1 = v[0] + v[1] + v[2] + v[3];
  float s2 = v[0]*v[0] + v[1]*v[1] + v[2]*v[2] + v[3]*v[3];
#pragma unroll
  for (int m = 32; m > 0; m >>= 1){ s1 += __shfl_xor(s1, m); s2 += __shfl_xor(s2, m); }
  __shared__ float ps1[4], ps2[4];
  int w = threadIdx.x >> 6;
  if ((threadIdx.x & 63) == 0){ ps1[w] = s1; ps2[w] = s2; }
  __syncthreads();
  s1 = ps1[0] + ps1[1] + ps1[2] + ps1[3];
  s2 = ps2[0] + ps2[1] + ps2[2] + ps2[3];
  float mu = s1 * (1.f / D_EMB);
  float var = s2 * (1.f / D_EMB) - mu * mu;
  float rs = rsqrtf(var + 1e-5f);
  ushort4 o;
  o.x = f2bf((v[0]-mu)*rs*g[c+0] + bb[c+0]);
  o.y = f2bf((v[1]-mu)*rs*g[c+1] + bb[c+1]);
  o.z = f2bf((v[2]-mu)*rs*g[c+2] + bb[c+2]);
  o.w = f2bf((v[3]-mu)*rs*g[c+3] + bb[c+3]);
  *(ushort4*)(out + (size_t)row * D_EMB + c) = o;
}

// ======== 2-phase GEMM template, A-panel-major block order (round 10) ========
// C = A[M,K] * Bt[N,K]^T, bf16 in, fp32 acc. BK=32, double-buffered LDS.
// ROUND-10 CHANGE: consecutive wg walk N (inner), so blocks sharing one A
// panel (256-512KB, L2-fits) run back-to-back on one XCD; A fetched ~once.
// Previous m-inner order re-streamed A once per n-column (FF1: 16x16MB).
// Swizzle (0-conflict, r7): read chunk ch=(lg+(row>>1))&3, inverse-permuted
// global source chunk, linear LDS.
template<int MODE, int BMT, int BNT, int NTHR>
__global__ __launch_bounds__(NTHR) void gemm2ph(
    const u16* __restrict__ A, const u16* __restrict__ Bt,
    int M, int N, int K,
    const float* __restrict__ bias0, const float* __restrict__ bias1,
    const float* __restrict__ bias2, const float* __restrict__ resid,
    void* __restrict__ o0, void* __restrict__ o1, void* __restrict__ o2)
{
  constexpr int NWAVE = NTHR/64;
  constexpr int WCN = BNT/64, WRN = NWAVE/WCN;
  static_assert(BMT/WRN == 64, "wave tile is 64x64");
  constexpr int RPP = NTHR/4;                    // rows staged per pass
  constexpr int ALD = (BMT*32)/(NTHR*8);         // 16B loads/thread for A
  constexpr int BLD = (BNT*32)/(NTHR*8);
  __shared__ alignas(16) u16 Al[2][BMT*32];
  __shared__ alignas(16) u16 Bl[2][BNT*32];

  const int tid = threadIdx.x;
  const int wid = tid>>6, lane = tid&63, lr = lane&15, lg = lane>>4;
  const int wr = wid/WCN, wc = wid%WCN;

  // XCD swizzle (all grids divisible by 8) + A-panel-major (n inner)
  const int gx = gridDim.x;
  const int gy = gridDim.y;
  const int nwg = gx * gy;
  const int bid = blockIdx.x + blockIdx.y*gx;
  const int wg = (bid&7)*(nwg>>3) + (bid>>3);
  const int m0 = (wg / gy) * BMT;    // consecutive wg share m0 (A panel)
  const int n0 = (wg % gy) * BNT;

  const int srow = tid>>2;                                   // staging row
  const int scs = (((tid&3) - ((srow>>1)&3)) & 3) * 8;       // inv-swizzled src chunk

  auto stage = [&](int buf, int kt){
    const u16* asrc = A + (size_t)(m0 + srow)*K + kt*32 + scs;
#pragma unroll
    for (int r = 0; r < ALD; ++r)
      gload_lds16(asrc + (size_t)(r*RPP)*K, &Al[buf][r*(NTHR*8) + tid*8]);
    const u16* bsrc = Bt + (size_t)(n0 + srow)*K + kt*32 + scs;
#pragma unroll
    for (int r = 0; r < BLD; ++r)
      gload_lds16(bsrc + (size_t)(r*RPP)*K, &Bl[buf][r*(NTHR*8) + tid*8]);
  };

  f32x4 acc[4][4];
#pragma unroll
  for (int i = 0; i < 4; i++)
#pragma unroll
    for (int j = 0; j < 4; j++) acc[i][j] = {0.f,0.f,0.f,0.f};

  const int nk = K/32;
  stage(0, 0);
  for (int kt = 0; kt < nk; ++kt){
    __syncthreads();                   // drains vmcnt: stage(kt) visible
    if (kt + 1 < nk) stage((kt+1)&1, kt+1);
    const int buf = kt & 1;
    s16x8 af[4], bf[4];
#pragma unroll
    for (int i = 0; i < 4; i++){
      const int ar = wr*64 + i*16 + lr;
      af[i] = *(const s16x8*)&Al[buf][ar*32 + (((lg + (ar>>1)) & 3)<<3)];
      const int br = wc*64 + i*16 + lr;
      bf[i] = *(const s16x8*)&Bl[buf][br*32 + (((lg + (br>>1)) & 3)<<3)];
    }
#pragma unroll
    for (int i = 0; i < 4; i++)
#pragma unroll
      for (int j = 0; j < 4; j++)
        acc[i][j] = __builtin_amdgcn_mfma_f32_16x16x32_bf16(af[i], bf[j], acc[i][j], 0, 0, 0);
  }

  // epilogue: lane holds C[row=lg*4+i][col=lr] per 16x16 fragment
#pragma unroll
  for (int fm = 0; fm < 4; fm++){
    const int gmb = m0 + wr*64 + fm*16 + lg*4;
#pragma unroll
    for (int fn = 0; fn < 4; fn++){
      const int gn = n0 + wc*64 + fn*16 + lr;
#pragma unroll
      for (int i = 0; i < 4; i++){
        const int gm = gmb + i;
        float v = acc[fm][fn][i];
        if (MODE == 0){
          const int cls = gn >> 10, nn = gn & 1023;
          if (cls == 0)      ((u16*)o0)[(size_t)gm * D_EMB + nn] = f2bf(v + bias0[nn]);
          else if (cls == 1) ((u16*)o1)[(size_t)gm * D_EMB + nn] = f2bf(v + bias1[nn]);
          else {
            const int hh = nn >> 6, ss = nn & 63, bb = gm >> 10, tt = gm & 1023;
            ((u16*)o2)[(((size_t)(bb * NH + hh)) * HS + ss) * NSEQ + tt] = f2bf(v + bias2[nn]);
          }
        } else if (MODE == 1){
          ((float*)o0)[(size_t)gm * N + gn] = resid[(size_t)gm * N + gn] + v + bias0[gn];
        } else {
          float y = v + bias0[gn];
          y = y > 0.f ? y : 0.01f * y;
          ((u16*)o0)[(size_t)gm * N + gn] = f2bf(y);
        }
      }
    }
  }
}

// ---------------- flash attention (round-3, unchanged) ----------------
__global__ __launch_bounds__(256) void attn_kernel(
    const u16* __restrict__ Qb, const u16* __restrict__ Kb, const u16* __restrict__ VT,
    u16* __restrict__ attnC)
{
  const int bid = blockIdx.x;
  const int bh = bid & 127, qt = bid >> 7;
  const int b = bh >> 4, h = bh & 15;
  const int tid = threadIdx.x, w = tid >> 6, lane = tid & 63;
  const int lr = lane & 15, lg = lane >> 4;
  const int q0 = qt * 128 + w * 32;

  __shared__ alignas(16) u16 Kl[2][64*64];
  __shared__ alignas(16) u16 Vl[2][64*64];
  __shared__ alignas(16) u16 Pl[4][32][72];

  const int srow = tid >> 3, scg = tid & 7;
  const u16* kbase = Kb + (size_t)(b * NSEQ) * D_EMB + h * HS;
  const u16* vbase = VT + ((size_t)(b * NH + h)) * HS * NSEQ;

  auto stage = [&](int buf, int kt){
    const int tk = kt * 64;
#pragma unroll
    for (int p = 0; p < 2; ++p){
      const int row = srow + p * 32;
      const int sc = scg ^ (row & 7);
      gload_lds16(kbase + (size_t)(tk + row) * D_EMB + sc * 8, &Kl[buf][(p * 256 + tid) * 8]);
      gload_lds16(vbase + (size_t)row * NSEQ + tk + sc * 8,    &Vl[buf][(p * 256 + tid) * 8]);
    }
  };

  s16x8 aq[2][2];
#pragma unroll
  for (int rb = 0; rb < 2; rb++)
#pragma unroll
    for (int kh = 0; kh < 2; kh++)
      aq[rb][kh] = *(const s16x8*)(Qb + (size_t)(b * NSEQ + q0 + rb * 16 + lr) * D_EMB
                                   + h * HS + kh * 32 + lg * 8);

  float m_i[2][4], l_i[2][4];
  f32x4 zero = {0.f, 0.f, 0.f, 0.f};
  f32x4 ao[2][4];
#pragma unroll
  for (int rb = 0; rb < 2; rb++)
#pragma unroll
    for (int i = 0; i < 4; i++){ m_i[rb][i] = -1e30f; l_i[rb][i] = 0.f; ao[rb][i] = zero; }

  const float scale = 0.125f;
  const int rsw = lr & 7;

  stage(0, 0);
  for (int kt = 0; kt < NSEQ / 64; ++kt){
    __syncthreads();
    if (kt + 1 < NSEQ / 64) stage((kt + 1) & 1, kt + 1);
    const int cur = kt & 1;

    f32x4 sv[2][4];
#pragma unroll
    for (int rb = 0; rb < 2; rb++)
#pragma unroll
      for (int fn = 0; fn < 4; fn++) sv[rb][fn] = zero;
#pragma unroll
    for (int fn = 0; fn < 4; fn++){
      const int krow = fn * 16 + lr;
#pragma unroll
      for (int kh = 0; kh < 2; kh++){
        const int chunk = (kh * 4 + lg) ^ rsw;
        s16x8 kf = *(const s16x8*)&Kl[cur][krow * 64 + chunk * 8];
        sv[0][fn] = __builtin_amdgcn_mfma_f32_16x16x32_bf16(aq[0][kh], kf, sv[0][fn], 0, 0, 0);
        sv[1][fn] = __builtin_amdgcn_mfma_f32_16x16x32_bf16(aq[1][kh], kf, sv[1][fn], 0, 0, 0);
      }
    }

#pragma unroll
    for (int rb = 0; rb < 2; rb++){
      float p[4][4];
#pragma unroll
      for (int i = 0; i < 4; i++){
        float s0 = sv[rb][0][i] * scale, s1 = sv[rb][1][i] * scale;
        float s2 = sv[rb][2][i] * scale, s3 = sv[rb][3][i] * scale;
        float rmax = fmaxf(fmaxf(s0, s1), fmaxf(s2, s3));
#pragma unroll
        for (int mm = 8; mm > 0; mm >>= 1) rmax = fmaxf(rmax, __shfl_xor(rmax, mm));
        float mnew = fmaxf(m_i[rb][i], rmax);
        float fac = __expf(m_i[rb][i] - mnew);
        float p0 = __expf(s0 - mnew), p1 = __expf(s1 - mnew);
        float p2 = __expf(s2 - mnew), p3 = __expf(s3 - mnew);
        p[0][i] = p0; p[1][i] = p1; p[2][i] = p2; p[3][i] = p3;
        float rs = (p0 + p1) + (p2 + p3);
#pragma unroll
        for (int mm = 8; mm > 0; mm >>= 1) rs += __shfl_xor(rs, mm);
        l_i[rb][i] = l_i[rb][i] * fac + rs;
        m_i[rb][i] = mnew;
#pragma unroll
        for (int fn = 0; fn < 4; fn++) ao[rb][fn][i] *= fac;
      }
#pragma unroll
      for (int fn = 0; fn < 4; fn++)
#pragma unroll
        for (int i = 0; i < 4; i++)
          Pl[w][rb * 16 + lg * 4 + i][fn * 16 + lr] = f2bf(p[fn][i]);
    }

    s16x8 vf[4][2];
#pragma unroll
    for (int fn = 0; fn < 4; fn++){
      const int vrow = fn * 16 + lr;
#pragma unroll
      for (int kh = 0; kh < 2; kh++){
        const int chunk = (kh * 4 + lg) ^ rsw;
        vf[fn][kh] = *(const s16x8*)&Vl[cur][vrow * 64 + chunk * 8];
      }
    }
#pragma unroll
    for (int rb = 0; rb < 2; rb++){
      s16x8 pa0 = *(const s16x8*)&Pl[w][rb * 16 + lr][lg * 8];
      s16x8 pa1 = *(const s16x8*)&Pl[w][rb * 16 + lr][32 + lg * 8];
#pragma unroll
      for (int fn = 0; fn < 4; fn++){
        ao[rb][fn] = __builtin_amdgcn_mfma_f32_16x16x32_bf16(pa0, vf[fn][0], ao[rb][fn], 0, 0, 0);
        ao[rb][fn] = __builtin_amdgcn_mfma_f32_16x16x32_bf16(pa1, vf[fn][1], ao[rb][fn], 0, 0, 0);
      }
    }
  }

#pragma unroll
  for (int rb = 0; rb < 2; rb++)
#pragma unroll
    for (int fn = 0; fn < 4; fn++)
#pragma unroll
      for (int i = 0; i < 4; i++){
        float v = ao[rb][fn][i] / l_i[rb][i];
        attnC[(size_t)(b * NSEQ + q0 + rb * 16 + lg * 4 + i) * D_EMB + h * HS + fn * 16 + lr] = f2bf(v);
      }
}

// ---------------- host ----------------
extern "C" void kernel_launch(void* const* d_in, const int* in_sizes, int n_in,
                              void* d_out, int out_size, void* d_ws, size_t ws_size,
                              hipStream_t stream)
{
  const float* x    = (const float*)d_in[0];
  const float* Wq   = (const float*)d_in[1];
  const float* bq   = (const float*)d_in[2];
  const float* Wk   = (const float*)d_in[3];
  const float* bk   = (const float*)d_in[4];
  const float* Wv   = (const float*)d_in[5];
  const float* bv   = (const float*)d_in[6];
  const float* Wp   = (const float*)d_in[7];
  const float* bp   = (const float*)d_in[8];
  const float* W1   = (const float*)d_in[9];
  const float* b1   = (const float*)d_in[10];
  const float* W2   = (const float*)d_in[11];
  const float* b2   = (const float*)d_in[12];
  const float* ln1g = (const float*)d_in[13];
  const float* ln1b = (const float*)d_in[14];
  const float* ln2g = (const float*)d_in[15];
  const float* ln2b = (const float*)d_in[16];
  float* out = (float*)d_out;

  char* ws = (char*)d_ws;
  size_t off = 0;
  auto mk = [&](size_t bytes)->void*{ void* p = ws + off; off += (bytes + 255) & ~(size_t)255; return p; };
  u16*  h1    = (u16*) mk((size_t)MTOT * D_EMB * 2);
  u16*  Qb    = (u16*) mk((size_t)MTOT * D_EMB * 2);
  u16*  Kb    = (u16*) mk((size_t)MTOT * D_EMB * 2);
  u16*  VTb   = (u16*) mk((size_t)MTOT * D_EMB * 2);
  u16*  attnC = (u16*) mk((size_t)MTOT * D_EMB * 2);
  float* x1   = (float*)mk((size_t)MTOT * D_EMB * 4);
  u16*  h2    = (u16*) mk((size_t)MTOT * D_EMB * 2);
  u16*  ffb   = (u16*) mk((size_t)MTOT * DFF * 2);
  u16*  WqkvT = (u16*) mk((size_t)3 * D_EMB * D_EMB * 2);
  u16*  WpT   = (u16*) mk((size_t)D_EMB * D_EMB * 2);
  u16*  W1T   = (u16*) mk((size_t)D_EMB * DFF * 2);
  u16*  W2T   = (u16*) mk((size_t)D_EMB * DFF * 2);

  dim3 tb(32, 8, 1);
  transpose_cvt<<<dim3(HS/32, D_EMB/32, NH), tb, 0, stream>>>(Wq, WqkvT,                         D_EMB, HS, (size_t)D_EMB*HS, (size_t)HS*D_EMB);
  transpose_cvt<<<dim3(HS/32, D_EMB/32, NH), tb, 0, stream>>>(Wk, WqkvT + (size_t)D_EMB*D_EMB,   D_EMB, HS, (size_t)D_EMB*HS, (size_t)HS*D_EMB);
  transpose_cvt<<<dim3(HS/32, D_EMB/32, NH), tb, 0, stream>>>(Wv, WqkvT + (size_t)2*D_EMB*D_EMB, D_EMB, HS, (size_t)D_EMB*HS, (size_t)HS*D_EMB);
  transpose_cvt<<<dim3(D_EMB/32, D_EMB/32, 1), tb, 0, stream>>>(Wp, WpT,  D_EMB, D_EMB, 0, 0);
  transpose_cvt<<<dim3(DFF/32,  D_EMB/32, 1), tb, 0, stream>>>(W1, W1T,  D_EMB, DFF,   0, 0);
  transpose_cvt<<<dim3(D_EMB/32, DFF/32,  1), tb, 0, stream>>>(W2, W2T,  DFF,   D_EMB, 0, 0);

  ln_kernel<<<MTOT, 256, 0, stream>>>(x, ln1g, ln1b, h1);

  // QKV: M=8192, N=3072, K=1024 — 128x256, 512 thr, grid 64x12=768
  gemm2ph<0,128,256,512><<<dim3(MTOT/128, 3*D_EMB/256), 512, 0, stream>>>(
      h1, WqkvT, MTOT, 3*D_EMB, D_EMB, bq, bk, bv, nullptr, Qb, Kb, VTb);

  attn_kernel<<<NB*NH*(NSEQ/128), 256, 0, stream>>>(Qb, Kb, VTb, attnC);

  // proj: M=8192, N=1024, K=1024 — 64x256, 256 thr, grid 128x4=512
  gemm2ph<1,64,256,256><<<dim3(MTOT/64, D_EMB/256), 256, 0, stream>>>(
      attnC, WpT, MTOT, D_EMB, D_EMB, bp, nullptr, nullptr, x, x1, nullptr, nullptr);

  ln_kernel<<<MTOT, 256, 0, stream>>>(x1, ln2g, ln2b, h2);

  // FF1: M=8192, N=4096, K=1024 — 128x256, grid 64x16=1024
  gemm2ph<2,128,256,512><<<dim3(MTOT/128, DFF/256), 512, 0, stream>>>(
      h2, W1T, MTOT, DFF, D_EMB, b1, nullptr, nullptr, nullptr, ffb, nullptr, nullptr);

  // FF2: M=8192, N=1024, K=4096 — 64x256, grid 128x4=512
  gemm2ph<1,64,256,256><<<dim3(MTOT/64, D_EMB/256), 256, 0, stream>>>(
      ffb, W2T, MTOT, D_EMB, DFF, b2, nullptr, nullptr, x1, out, nullptr, nullptr);
}

// Round 11
// 464.782 us; speedup vs baseline: 1.0863x; 1.0052x over previous
//
#include <hip/hip_runtime.h>
#include <cstdint>
#include <cstddef>

typedef unsigned short u16;
typedef __attribute__((ext_vector_type(4))) float f32x4;
typedef __attribute__((ext_vector_type(8))) short s16x8;

#define D_EMB 1024
#define NSEQ 1024
#define NB 8
#define NH 16
#define HS 64
#define DFF 4096
#define MTOT (NB*NSEQ)

__device__ __forceinline__ u16 f2bf(float f){
  unsigned u = __float_as_uint(f);
  u += 0x7FFFu + ((u >> 16) & 1u);     // round-to-nearest-even
  return (u16)(u >> 16);
}

__device__ __forceinline__ void gload_lds16(const void* g, void* l){
  __builtin_amdgcn_global_load_lds((const __attribute__((address_space(1))) void*)g,
                                   (__attribute__((address_space(3))) void*)l, 16, 0, 0);
}

// ---------------- tiled transpose + fp32->bf16 convert ----------------
__global__ void transpose_cvt(const float* __restrict__ in, u16* __restrict__ out,
                              int R, int C, size_t inStride, size_t outStride){
  __shared__ float t[32][33];
  const float* ip = in + (size_t)blockIdx.z * inStride;
  u16* op = out + (size_t)blockIdx.z * outStride;
  int c0 = blockIdx.x * 32, r0 = blockIdx.y * 32;
  int tx = threadIdx.x, ty = threadIdx.y;
#pragma unroll
  for (int j = 0; j < 32; j += 8)
    t[ty + j][tx] = ip[(size_t)(r0 + ty + j) * C + (c0 + tx)];
  __syncthreads();
#pragma unroll
  for (int j = 0; j < 32; j += 8)
    op[(size_t)(c0 + ty + j) * R + (r0 + tx)] = f2bf(t[tx][ty + j]);
}

// ---------------- LayerNorm (fp32 in, bf16 out) ----------------
__global__ __launch_bounds__(256) void ln_kernel(const float* __restrict__ x,
    const float* __restrict__ g, const float* __restrict__ bb, u16* __restrict__ out){
  int row = blockIdx.x;
  const float* xr = x + (size_t)row * D_EMB;
  int c = threadIdx.x * 4;
  f32x4 v = *(const f32x4*)(xr + c);
  float s1 = v[0] + v[1] + v[2] + v[3];
  float s2 = v[0]*v[0] + v[1]*v[1] + v[2]*v[2] + v[3]*v[3];
#pragma unroll
  for (int m = 32; m > 0; m >>= 1){ s1 += __shfl_xor(s1, m); s2 += __shfl_xor(s2, m); }
  __shared__ float ps1[4], ps2[4];
  int w = threadIdx.x >> 6;
  if ((threadIdx.x & 63) == 0){ ps1[w] = s1; ps2[w] = s2; }
  __syncthreads();
  s1 = ps1[0] + ps1[1] + ps1[2] + ps1[3];
  s2 = ps2[0] + ps2[1] + ps2[2] + ps2[3];
  float mu = s1 * (1.f / D_EMB);
  float var = s2 * (1.f / D_EMB) - mu * mu;
  float rs = rsqrtf(var + 1e-5f);
  ushort4 o;
  o.x = f2bf((v[0]-mu)*rs*g[c+0] + bb[c+0]);
  o.y = f2bf((v[1]-mu)*rs*g[c+1] + bb[c+1]);
  o.z = f2bf((v[2]-mu)*rs*g[c+2] + bb[c+2]);
  o.w = f2bf((v[3]-mu)*rs*g[c+3] + bb[c+3]);
  *(ushort4*)(out + (size_t)row * D_EMB + c) = o;
}

// ======== 2-phase GEMM template, A-panel-major block order ========
// C = A[M,K] * Bt[N,K]^T, bf16 in, fp32 acc. BK=32, double-buffered LDS.
// A-panel-major: consecutive wg walk N, so blocks sharing an A panel run
// back-to-back on one XCD (A fetched ~once). Swizzle (0-conflict, r7):
// read chunk ch=(lg+(row>>1))&3, inverse-permuted global src, linear LDS.
// ROUND-11: MODE 0 writes Q pre-scaled by 0.125 (exact pow2) so attn's
// softmax drops the per-tile scale multiplies.
template<int MODE, int BMT, int BNT, int NTHR>
__global__ __launch_bounds__(NTHR) void gemm2ph(
    const u16* __restrict__ A, const u16* __restrict__ Bt,
    int M, int N, int K,
    const float* __restrict__ bias0, const float* __restrict__ bias1,
    const float* __restrict__ bias2, const float* __restrict__ resid,
    void* __restrict__ o0, void* __restrict__ o1, void* __restrict__ o2)
{
  constexpr int NWAVE = NTHR/64;
  constexpr int WCN = BNT/64, WRN = NWAVE/WCN;
  static_assert(BMT/WRN == 64, "wave tile is 64x64");
  constexpr int RPP = NTHR/4;                    // rows staged per pass
  constexpr int ALD = (BMT*32)/(NTHR*8);         // 16B loads/thread for A
  constexpr int BLD = (BNT*32)/(NTHR*8);
  __shared__ alignas(16) u16 Al[2][BMT*32];
  __shared__ alignas(16) u16 Bl[2][BNT*32];

  const int tid = threadIdx.x;
  const int wid = tid>>6, lane = tid&63, lr = lane&15, lg = lane>>4;
  const int wr = wid/WCN, wc = wid%WCN;

  // XCD swizzle (all grids divisible by 8) + A-panel-major (n inner)
  const int gx = gridDim.x;
  const int gy = gridDim.y;
  const int nwg = gx * gy;
  const int bid = blockIdx.x + blockIdx.y*gx;
  const int wg = (bid&7)*(nwg>>3) + (bid>>3);
  const int m0 = (wg / gy) * BMT;    // consecutive wg share m0 (A panel)
  const int n0 = (wg % gy) * BNT;

  const int srow = tid>>2;                                   // staging row
  const int scs = (((tid&3) - ((srow>>1)&3)) & 3) * 8;       // inv-swizzled src chunk

  auto stage = [&](int buf, int kt){
    const u16* asrc = A + (size_t)(m0 + srow)*K + kt*32 + scs;
#pragma unroll
    for (int r = 0; r < ALD; ++r)
      gload_lds16(asrc + (size_t)(r*RPP)*K, &Al[buf][r*(NTHR*8) + tid*8]);
    const u16* bsrc = Bt + (size_t)(n0 + srow)*K + kt*32 + scs;
#pragma unroll
    for (int r = 0; r < BLD; ++r)
      gload_lds16(bsrc + (size_t)(r*RPP)*K, &Bl[buf][r*(NTHR*8) + tid*8]);
  };

  f32x4 acc[4][4];
#pragma unroll
  for (int i = 0; i < 4; i++)
#pragma unroll
    for (int j = 0; j < 4; j++) acc[i][j] = {0.f,0.f,0.f,0.f};

  const int nk = K/32;
  stage(0, 0);
  for (int kt = 0; kt < nk; ++kt){
    __syncthreads();                   // drains vmcnt: stage(kt) visible
    if (kt + 1 < nk) stage((kt+1)&1, kt+1);
    const int buf = kt & 1;
    s16x8 af[4], bf[4];
#pragma unroll
    for (int i = 0; i < 4; i++){
      const int ar = wr*64 + i*16 + lr;
      af[i] = *(const s16x8*)&Al[buf][ar*32 + (((lg + (ar>>1)) & 3)<<3)];
      const int br = wc*64 + i*16 + lr;
      bf[i] = *(const s16x8*)&Bl[buf][br*32 + (((lg + (br>>1)) & 3)<<3)];
    }
#pragma unroll
    for (int i = 0; i < 4; i++)
#pragma unroll
      for (int j = 0; j < 4; j++)
        acc[i][j] = __builtin_amdgcn_mfma_f32_16x16x32_bf16(af[i], bf[j], acc[i][j], 0, 0, 0);
  }

  // epilogue: lane holds C[row=lg*4+i][col=lr] per 16x16 fragment
#pragma unroll
  for (int fm = 0; fm < 4; fm++){
    const int gmb = m0 + wr*64 + fm*16 + lg*4;
#pragma unroll
    for (int fn = 0; fn < 4; fn++){
      const int gn = n0 + wc*64 + fn*16 + lr;
#pragma unroll
      for (int i = 0; i < 4; i++){
        const int gm = gmb + i;
        float v = acc[fm][fn][i];
        if (MODE == 0){
          const int cls = gn >> 10, nn = gn & 1023;
          if (cls == 0)      ((u16*)o0)[(size_t)gm * D_EMB + nn] = f2bf((v + bias0[nn]) * 0.125f);
          else if (cls == 1) ((u16*)o1)[(size_t)gm * D_EMB + nn] = f2bf(v + bias1[nn]);
          else {
            const int hh = nn >> 6, ss = nn & 63, bb = gm >> 10, tt = gm & 1023;
            ((u16*)o2)[(((size_t)(bb * NH + hh)) * HS + ss) * NSEQ + tt] = f2bf(v + bias2[nn]);
          }
        } else if (MODE == 1){
          ((float*)o0)[(size_t)gm * N + gn] = resid[(size_t)gm * N + gn] + v + bias0[gn];
        } else {
          float y = v + bias0[gn];
          y = y > 0.f ? y : 0.01f * y;
          ((u16*)o0)[(size_t)gm * N + gn] = f2bf(y);
        }
      }
    }
  }
}

// ---------------- flash attention (round-11: lean softmax) ----------------
// Q arrives pre-scaled by 1/sqrt(64) (folded into QKV epilogue).
// l_i kept as PER-LANE partial (no per-tile cross-lane sum reduce; linearity
// of online softmax) - reduced once after the KV loop.
// Defer-max (T13, THR=8): wave-uniform __any branch skips the rescale pass
// (fac exp + 8 muls + m update) when no row grew; P bounded by e^8 (f32/bf16
// headroom fine). First tile takes the branch with fac=exp(-inf)=0.
__global__ __launch_bounds__(256) void attn_kernel(
    const u16* __restrict__ Qb, const u16* __restrict__ Kb, const u16* __restrict__ VT,
    u16* __restrict__ attnC)
{
  const int bid = blockIdx.x;
  const int bh = bid & 127, qt = bid >> 7;
  const int b = bh >> 4, h = bh & 15;
  const int tid = threadIdx.x, w = tid >> 6, lane = tid & 63;
  const int lr = lane & 15, lg = lane >> 4;
  const int q0 = qt * 128 + w * 32;

  __shared__ alignas(16) u16 Kl[2][64*64];
  __shared__ alignas(16) u16 Vl[2][64*64];
  __shared__ alignas(16) u16 Pl[4][32][72];

  const int srow = tid >> 3, scg = tid & 7;
  const u16* kbase = Kb + (size_t)(b * NSEQ) * D_EMB + h * HS;
  const u16* vbase = VT + ((size_t)(b * NH + h)) * HS * NSEQ;

  auto stage = [&](int buf, int kt){
    const int tk = kt * 64;
#pragma unroll
    for (int p = 0; p < 2; ++p){
      const int row = srow + p * 32;
      const int sc = scg ^ (row & 7);
      gload_lds16(kbase + (size_t)(tk + row) * D_EMB + sc * 8, &Kl[buf][(p * 256 + tid) * 8]);
      gload_lds16(vbase + (size_t)row * NSEQ + tk + sc * 8,    &Vl[buf][(p * 256 + tid) * 8]);
    }
  };

  s16x8 aq[2][2];
#pragma unroll
  for (int rb = 0; rb < 2; rb++)
#pragma unroll
    for (int kh = 0; kh < 2; kh++)
      aq[rb][kh] = *(const s16x8*)(Qb + (size_t)(b * NSEQ + q0 + rb * 16 + lr) * D_EMB
                                   + h * HS + kh * 32 + lg * 8);

  float m_i[2][4], l_i[2][4];
  f32x4 zero = {0.f, 0.f, 0.f, 0.f};
  f32x4 ao[2][4];
#pragma unroll
  for (int rb = 0; rb < 2; rb++)
#pragma unroll
    for (int i = 0; i < 4; i++){ m_i[rb][i] = -1e30f; l_i[rb][i] = 0.f; ao[rb][i] = zero; }

  const int rsw = lr & 7;

  stage(0, 0);
  for (int kt = 0; kt < NSEQ / 64; ++kt){
    __syncthreads();
    if (kt + 1 < NSEQ / 64) stage((kt + 1) & 1, kt + 1);
    const int cur = kt & 1;

    f32x4 sv[2][4];
#pragma unroll
    for (int rb = 0; rb < 2; rb++)
#pragma unroll
      for (int fn = 0; fn < 4; fn++) sv[rb][fn] = zero;
#pragma unroll
    for (int fn = 0; fn < 4; fn++){
      const int krow = fn * 16 + lr;
#pragma unroll
      for (int kh = 0; kh < 2; kh++){
        const int chunk = (kh * 4 + lg) ^ rsw;
        s16x8 kf = *(const s16x8*)&Kl[cur][krow * 64 + chunk * 8];
        sv[0][fn] = __builtin_amdgcn_mfma_f32_16x16x32_bf16(aq[0][kh], kf, sv[0][fn], 0, 0, 0);
        sv[1][fn] = __builtin_amdgcn_mfma_f32_16x16x32_bf16(aq[1][kh], kf, sv[1][fn], 0, 0, 0);
      }
    }

#pragma unroll
    for (int rb = 0; rb < 2; rb++){
      float p[4][4];
#pragma unroll
      for (int i = 0; i < 4; i++){
        float s0 = sv[rb][0][i], s1 = sv[rb][1][i];
        float s2 = sv[rb][2][i], s3 = sv[rb][3][i];
        float rmax = fmaxf(fmaxf(s0, s1), fmaxf(s2, s3));
#pragma unroll
        for (int mm = 8; mm > 0; mm >>= 1) rmax = fmaxf(rmax, __shfl_xor(rmax, mm));
        if (__any(rmax > m_i[rb][i] + 8.0f)){       // wave-uniform rescale (rare)
          float mnew = fmaxf(m_i[rb][i], rmax);
          float fac = __expf(m_i[rb][i] - mnew);
          l_i[rb][i] *= fac;
#pragma unroll
          for (int fn = 0; fn < 4; fn++) ao[rb][fn][i] *= fac;
          m_i[rb][i] = mnew;
        }
        const float m = m_i[rb][i];
        float p0 = __expf(s0 - m), p1 = __expf(s1 - m);
        float p2 = __expf(s2 - m), p3 = __expf(s3 - m);
        p[0][i] = p0; p[1][i] = p1; p[2][i] = p2; p[3][i] = p3;
        l_i[rb][i] += (p0 + p1) + (p2 + p3);        // per-lane partial sum
      }
#pragma unroll
      for (int fn = 0; fn < 4; fn++)
#pragma unroll
        for (int i = 0; i < 4; i++)
          Pl[w][rb * 16 + lg * 4 + i][fn * 16 + lr] = f2bf(p[fn][i]);
    }

    s16x8 vf[4][2];
#pragma unroll
    for (int fn = 0; fn < 4; fn++){
      const int vrow = fn * 16 + lr;
#pragma unroll
      for (int kh = 0; kh < 2; kh++){
        const int chunk = (kh * 4 + lg) ^ rsw;
        vf[fn][kh] = *(const s16x8*)&Vl[cur][vrow * 64 + chunk * 8];
      }
    }
#pragma unroll
    for (int rb = 0; rb < 2; rb++){
      s16x8 pa0 = *(const s16x8*)&Pl[w][rb * 16 + lr][lg * 8];
      s16x8 pa1 = *(const s16x8*)&Pl[w][rb * 16 + lr][32 + lg * 8];
#pragma unroll
      for (int fn = 0; fn < 4; fn++){
        ao[rb][fn] = __builtin_amdgcn_mfma_f32_16x16x32_bf16(pa0, vf[fn][0], ao[rb][fn], 0, 0, 0);
        ao[rb][fn] = __builtin_amdgcn_mfma_f32_16x16x32_bf16(pa1, vf[fn][1], ao[rb][fn], 0, 0, 0);
      }
    }
  }

  // final cross-lane sum of the per-lane l partials (16 lr lanes per row)
#pragma unroll
  for (int rb = 0; rb < 2; rb++)
#pragma unroll
    for (int i = 0; i < 4; i++)
#pragma unroll
      for (int mm = 8; mm > 0; mm >>= 1) l_i[rb][i] += __shfl_xor(l_i[rb][i], mm);

#pragma unroll
  for (int rb = 0; rb < 2; rb++)
#pragma unroll
    for (int fn = 0; fn < 4; fn++)
#pragma unroll
      for (int i = 0; i < 4; i++){
        float v = ao[rb][fn][i] / l_i[rb][i];
        attnC[(size_t)(b * NSEQ + q0 + rb * 16 + lg * 4 + i) * D_EMB + h * HS + fn * 16 + lr] = f2bf(v);
      }
}

// ---------------- host ----------------
extern "C" void kernel_launch(void* const* d_in, const int* in_sizes, int n_in,
                              void* d_out, int out_size, void* d_ws, size_t ws_size,
                              hipStream_t stream)
{
  const float* x    = (const float*)d_in[0];
  const float* Wq   = (const float*)d_in[1];
  const float* bq   = (const float*)d_in[2];
  const float* Wk   = (const float*)d_in[3];
  const float* bk   = (const float*)d_in[4];
  const float* Wv   = (const float*)d_in[5];
  const float* bv   = (const float*)d_in[6];
  const float* Wp   = (const float*)d_in[7];
  const float* bp   = (const float*)d_in[8];
  const float* W1   = (const float*)d_in[9];
  const float* b1   = (const float*)d_in[10];
  const float* W2   = (const float*)d_in[11];
  const float* b2   = (const float*)d_in[12];
  const float* ln1g = (const float*)d_in[13];
  const float* ln1b = (const float*)d_in[14];
  const float* ln2g = (const float*)d_in[15];
  const float* ln2b = (const float*)d_in[16];
  float* out = (float*)d_out;

  char* ws = (char*)d_ws;
  size_t off = 0;
  auto mk = [&](size_t bytes)->void*{ void* p = ws + off; off += (bytes + 255) & ~(size_t)255; return p; };
  u16*  h1    = (u16*) mk((size_t)MTOT * D_EMB * 2);
  u16*  Qb    = (u16*) mk((size_t)MTOT * D_EMB * 2);
  u16*  Kb    = (u16*) mk((size_t)MTOT * D_EMB * 2);
  u16*  VTb   = (u16*) mk((size_t)MTOT * D_EMB * 2);
  u16*  attnC = (u16*) mk((size_t)MTOT * D_EMB * 2);
  float* x1   = (float*)mk((size_t)MTOT * D_EMB * 4);
  u16*  h2    = (u16*) mk((size_t)MTOT * D_EMB * 2);
  u16*  ffb   = (u16*) mk((size_t)MTOT * DFF * 2);
  u16*  WqkvT = (u16*) mk((size_t)3 * D_EMB * D_EMB * 2);
  u16*  WpT   = (u16*) mk((size_t)D_EMB * D_EMB * 2);
  u16*  W1T   = (u16*) mk((size_t)D_EMB * DFF * 2);
  u16*  W2T   = (u16*) mk((size_t)D_EMB * DFF * 2);

  dim3 tb(32, 8, 1);
  transpose_cvt<<<dim3(HS/32, D_EMB/32, NH), tb, 0, stream>>>(Wq, WqkvT,                         D_EMB, HS, (size_t)D_EMB*HS, (size_t)HS*D_EMB);
  transpose_cvt<<<dim3(HS/32, D_EMB/32, NH), tb, 0, stream>>>(Wk, WqkvT + (size_t)D_EMB*D_EMB,   D_EMB, HS, (size_t)D_EMB*HS, (size_t)HS*D_EMB);
  transpose_cvt<<<dim3(HS/32, D_EMB/32, NH), tb, 0, stream>>>(Wv, WqkvT + (size_t)2*D_EMB*D_EMB, D_EMB, HS, (size_t)D_EMB*HS, (size_t)HS*D_EMB);
  transpose_cvt<<<dim3(D_EMB/32, D_EMB/32, 1), tb, 0, stream>>>(Wp, WpT,  D_EMB, D_EMB, 0, 0);
  transpose_cvt<<<dim3(DFF/32,  D_EMB/32, 1), tb, 0, stream>>>(W1, W1T,  D_EMB, DFF,   0, 0);
  transpose_cvt<<<dim3(D_EMB/32, DFF/32,  1), tb, 0, stream>>>(W2, W2T,  DFF,   D_EMB, 0, 0);

  ln_kernel<<<MTOT, 256, 0, stream>>>(x, ln1g, ln1b, h1);

  // QKV: M=8192, N=3072, K=1024 — 128x256, 512 thr, grid 64x12=768
  gemm2ph<0,128,256,512><<<dim3(MTOT/128, 3*D_EMB/256), 512, 0, stream>>>(
      h1, WqkvT, MTOT, 3*D_EMB, D_EMB, bq, bk, bv, nullptr, Qb, Kb, VTb);

  attn_kernel<<<NB*NH*(NSEQ/128), 256, 0, stream>>>(Qb, Kb, VTb, attnC);

  // proj: M=8192, N=1024, K=1024 — 64x256, 256 thr, grid 128x4=512
  gemm2ph<1,64,256,256><<<dim3(MTOT/64, D_EMB/256), 256, 0, stream>>>(
      attnC, WpT, MTOT, D_EMB, D_EMB, bp, nullptr, nullptr, x, x1, nullptr, nullptr);

  ln_kernel<<<MTOT, 256, 0, stream>>>(x1, ln2g, ln2b, h2);

  // FF1: M=8192, N=4096, K=1024 — 128x256, grid 64x16=1024
  gemm2ph<2,128,256,512><<<dim3(MTOT/128, DFF/256), 512, 0, stream>>>(
      h2, W1T, MTOT, DFF, D_EMB, b1, nullptr, nullptr, nullptr, ffb, nullptr, nullptr);

  // FF2: M=8192, N=1024, K=4096 — 64x256, grid 128x4=512
  gemm2ph<1,64,256,256><<<dim3(MTOT/64, D_EMB/256), 256, 0, stream>>>(
      ffb, W2T, MTOT, D_EMB, DFF, b2, nullptr, nullptr, x1, out, nullptr, nullptr);
}

// Round 12
// 451.771 us; speedup vs baseline: 1.1175x; 1.0288x over previous
//
#include <hip/hip_runtime.h>
#include <cstdint>
#include <cstddef>

typedef unsigned short u16;
typedef __attribute__((ext_vector_type(4))) float f32x4;
typedef __attribute__((ext_vector_type(8))) short s16x8;

#define D_EMB 1024
#define NSEQ 1024
#define NB 8
#define NH 16
#define HS 64
#define DFF 4096
#define MTOT (NB*NSEQ)

__device__ __forceinline__ u16 f2bf(float f){
  unsigned u = __float_as_uint(f);
  u += 0x7FFFu + ((u >> 16) & 1u);     // round-to-nearest-even
  return (u16)(u >> 16);
}

__device__ __forceinline__ void gload_lds16(const void* g, void* l){
  __builtin_amdgcn_global_load_lds((const __attribute__((address_space(1))) void*)g,
                                   (__attribute__((address_space(3))) void*)l, 16, 0, 0);
}

// ---------------- tiled transpose + fp32->bf16 convert ----------------
__global__ void transpose_cvt(const float* __restrict__ in, u16* __restrict__ out,
                              int R, int C, size_t inStride, size_t outStride){
  __shared__ float t[32][33];
  const float* ip = in + (size_t)blockIdx.z * inStride;
  u16* op = out + (size_t)blockIdx.z * outStride;
  int c0 = blockIdx.x * 32, r0 = blockIdx.y * 32;
  int tx = threadIdx.x, ty = threadIdx.y;
#pragma unroll
  for (int j = 0; j < 32; j += 8)
    t[ty + j][tx] = ip[(size_t)(r0 + ty + j) * C + (c0 + tx)];
  __syncthreads();
#pragma unroll
  for (int j = 0; j < 32; j += 8)
    op[(size_t)(c0 + ty + j) * R + (r0 + tx)] = f2bf(t[tx][ty + j]);
}

// ---------------- LayerNorm (fp32 in, bf16 out) ----------------
__global__ __launch_bounds__(256) void ln_kernel(const float* __restrict__ x,
    const float* __restrict__ g, const float* __restrict__ bb, u16* __restrict__ out){
  int row = blockIdx.x;
  const float* xr = x + (size_t)row * D_EMB;
  int c = threadIdx.x * 4;
  f32x4 v = *(const f32x4*)(xr + c);
  float s1 = v[0] + v[1] + v[2] + v[3];
  float s2 = v[0]*v[0] + v[1]*v[1] + v[2]*v[2] + v[3]*v[3];
#pragma unroll
  for (int m = 32; m > 0; m >>= 1){ s1 += __shfl_xor(s1, m); s2 += __shfl_xor(s2, m); }
  __shared__ float ps1[4], ps2[4];
  int w = threadIdx.x >> 6;
  if ((threadIdx.x & 63) == 0){ ps1[w] = s1; ps2[w] = s2; }
  __syncthreads();
  s1 = ps1[0] + ps1[1] + ps1[2] + ps1[3];
  s2 = ps2[0] + ps2[1] + ps2[2] + ps2[3];
  float mu = s1 * (1.f / D_EMB);
  float var = s2 * (1.f / D_EMB) - mu * mu;
  float rs = rsqrtf(var + 1e-5f);
  ushort4 o;
  o.x = f2bf((v[0]-mu)*rs*g[c+0] + bb[c+0]);
  o.y = f2bf((v[1]-mu)*rs*g[c+1] + bb[c+1]);
  o.z = f2bf((v[2]-mu)*rs*g[c+2] + bb[c+2]);
  o.w = f2bf((v[3]-mu)*rs*g[c+3] + bb[c+3]);
  *(ushort4*)(out + (size_t)row * D_EMB + c) = o;
}

// ======== 2-phase GEMM template, A-panel-major block order ========
// C = A[M,K] * Bt[N,K]^T, bf16 in, fp32 acc. BK=32, double-buffered LDS.
// A-panel-major: consecutive wg walk N so blocks sharing an A panel run
// back-to-back on one XCD. Swizzle (0-conflict, r7): read chunk
// ch=(lg+(row>>1))&3, inverse-permuted global src, linear LDS.
// ROUND-12: RF generalized (wave tile = RF*16 x 64). N=1024 GEMMs use
// 64x128 blocks / 256 thr / wave tile 32x64 -> 1024 blocks = 4/CU (TLP).
template<int MODE, int BMT, int BNT, int NTHR>
__global__ __launch_bounds__(NTHR) void gemm2ph(
    const u16* __restrict__ A, const u16* __restrict__ Bt,
    int M, int N, int K,
    const float* __restrict__ bias0, const float* __restrict__ bias1,
    const float* __restrict__ bias2, const float* __restrict__ resid,
    void* __restrict__ o0, void* __restrict__ o1, void* __restrict__ o2)
{
  constexpr int NWAVE = NTHR/64;
  constexpr int WCN = BNT/64, WRN = NWAVE/WCN;
  constexpr int WROWS = BMT/WRN;                 // rows per wave
  constexpr int RF = WROWS/16;                   // row fragments per wave
  static_assert(RF*16*WRN == BMT, "wave tiling must cover BMT");
  constexpr int RPP = NTHR/4;                    // rows staged per pass
  constexpr int ALD = (BMT*32)/(NTHR*8);         // 16B loads/thread for A
  constexpr int BLD = (BNT*32)/(NTHR*8);
  __shared__ alignas(16) u16 Al[2][BMT*32];
  __shared__ alignas(16) u16 Bl[2][BNT*32];

  const int tid = threadIdx.x;
  const int wid = tid>>6, lane = tid&63, lr = lane&15, lg = lane>>4;
  const int wr = wid/WCN, wc = wid%WCN;

  // XCD swizzle (all grids divisible by 8) + A-panel-major (n inner)
  const int gx = gridDim.x;
  const int gy = gridDim.y;
  const int nwg = gx * gy;
  const int bid = blockIdx.x + blockIdx.y*gx;
  const int wg = (bid&7)*(nwg>>3) + (bid>>3);
  const int m0 = (wg / gy) * BMT;    // consecutive wg share m0 (A panel)
  const int n0 = (wg % gy) * BNT;

  const int srow = tid>>2;                                   // staging row
  const int scs = (((tid&3) - ((srow>>1)&3)) & 3) * 8;       // inv-swizzled src chunk

  auto stage = [&](int buf, int kt){
    const u16* asrc = A + (size_t)(m0 + srow)*K + kt*32 + scs;
#pragma unroll
    for (int r = 0; r < ALD; ++r)
      gload_lds16(asrc + (size_t)(r*RPP)*K, &Al[buf][r*(NTHR*8) + tid*8]);
    const u16* bsrc = Bt + (size_t)(n0 + srow)*K + kt*32 + scs;
#pragma unroll
    for (int r = 0; r < BLD; ++r)
      gload_lds16(bsrc + (size_t)(r*RPP)*K, &Bl[buf][r*(NTHR*8) + tid*8]);
  };

  f32x4 acc[RF][4];
#pragma unroll
  for (int i = 0; i < RF; i++)
#pragma unroll
    for (int j = 0; j < 4; j++) acc[i][j] = {0.f,0.f,0.f,0.f};

  const int nk = K/32;
  stage(0, 0);
  for (int kt = 0; kt < nk; ++kt){
    __syncthreads();                   // drains vmcnt: stage(kt) visible
    if (kt + 1 < nk) stage((kt+1)&1, kt+1);
    const int buf = kt & 1;
    s16x8 af[RF], bf[4];
#pragma unroll
    for (int i = 0; i < RF; i++){
      const int ar = wr*WROWS + i*16 + lr;
      af[i] = *(const s16x8*)&Al[buf][ar*32 + (((lg + (ar>>1)) & 3)<<3)];
    }
#pragma unroll
    for (int j = 0; j < 4; j++){
      const int br = wc*64 + j*16 + lr;
      bf[j] = *(const s16x8*)&Bl[buf][br*32 + (((lg + (br>>1)) & 3)<<3)];
    }
#pragma unroll
    for (int i = 0; i < RF; i++)
#pragma unroll
      for (int j = 0; j < 4; j++)
        acc[i][j] = __builtin_amdgcn_mfma_f32_16x16x32_bf16(af[i], bf[j], acc[i][j], 0, 0, 0);
  }

  // epilogue: lane holds C[row=lg*4+i][col=lr] per 16x16 fragment
#pragma unroll
  for (int fm = 0; fm < RF; fm++){
    const int gmb = m0 + wr*WROWS + fm*16 + lg*4;
#pragma unroll
    for (int fn = 0; fn < 4; fn++){
      const int gn = n0 + wc*64 + fn*16 + lr;
#pragma unroll
      for (int i = 0; i < 4; i++){
        const int gm = gmb + i;
        float v = acc[fm][fn][i];
        if (MODE == 0){
          const int cls = gn >> 10, nn = gn & 1023;
          if (cls == 0)      ((u16*)o0)[(size_t)gm * D_EMB + nn] = f2bf((v + bias0[nn]) * 0.125f);
          else if (cls == 1) ((u16*)o1)[(size_t)gm * D_EMB + nn] = f2bf(v + bias1[nn]);
          else {
            const int hh = nn >> 6, ss = nn & 63, bb = gm >> 10, tt = gm & 1023;
            ((u16*)o2)[(((size_t)(bb * NH + hh)) * HS + ss) * NSEQ + tt] = f2bf(v + bias2[nn]);
          }
        } else if (MODE == 1){
          ((float*)o0)[(size_t)gm * N + gn] = resid[(size_t)gm * N + gn] + v + bias0[gn];
        } else {
          float y = v + bias0[gn];
          y = y > 0.f ? y : 0.01f * y;
          ((u16*)o0)[(size_t)gm * N + gn] = f2bf(y);
        }
      }
    }
  }
}

// ---------------- flash attention (round-11 lean softmax, unchanged) ----------------
__global__ __launch_bounds__(256) void attn_kernel(
    const u16* __restrict__ Qb, const u16* __restrict__ Kb, const u16* __restrict__ VT,
    u16* __restrict__ attnC)
{
  const int bid = blockIdx.x;
  const int bh = bid & 127, qt = bid >> 7;
  const int b = bh >> 4, h = bh & 15;
  const int tid = threadIdx.x, w = tid >> 6, lane = tid & 63;
  const int lr = lane & 15, lg = lane >> 4;
  const int q0 = qt * 128 + w * 32;

  __shared__ alignas(16) u16 Kl[2][64*64];
  __shared__ alignas(16) u16 Vl[2][64*64];
  __shared__ alignas(16) u16 Pl[4][32][72];

  const int srow = tid >> 3, scg = tid & 7;
  const u16* kbase = Kb + (size_t)(b * NSEQ) * D_EMB + h * HS;
  const u16* vbase = VT + ((size_t)(b * NH + h)) * HS * NSEQ;

  auto stage = [&](int buf, int kt){
    const int tk = kt * 64;
#pragma unroll
    for (int p = 0; p < 2; ++p){
      const int row = srow + p * 32;
      const int sc = scg ^ (row & 7);
      gload_lds16(kbase + (size_t)(tk + row) * D_EMB + sc * 8, &Kl[buf][(p * 256 + tid) * 8]);
      gload_lds16(vbase + (size_t)row * NSEQ + tk + sc * 8,    &Vl[buf][(p * 256 + tid) * 8]);
    }
  };

  s16x8 aq[2][2];
#pragma unroll
  for (int rb = 0; rb < 2; rb++)
#pragma unroll
    for (int kh = 0; kh < 2; kh++)
      aq[rb][kh] = *(const s16x8*)(Qb + (size_t)(b * NSEQ + q0 + rb * 16 + lr) * D_EMB
                                   + h * HS + kh * 32 + lg * 8);

  float m_i[2][4], l_i[2][4];
  f32x4 zero = {0.f, 0.f, 0.f, 0.f};
  f32x4 ao[2][4];
#pragma unroll
  for (int rb = 0; rb < 2; rb++)
#pragma unroll
    for (int i = 0; i < 4; i++){ m_i[rb][i] = -1e30f; l_i[rb][i] = 0.f; ao[rb][i] = zero; }

  const int rsw = lr & 7;

  stage(0, 0);
  for (int kt = 0; kt < NSEQ / 64; ++kt){
    __syncthreads();
    if (kt + 1 < NSEQ / 64) stage((kt + 1) & 1, kt + 1);
    const int cur = kt & 1;

    f32x4 sv[2][4];
#pragma unroll
    for (int rb = 0; rb < 2; rb++)
#pragma unroll
      for (int fn = 0; fn < 4; fn++) sv[rb][fn] = zero;
#pragma unroll
    for (int fn = 0; fn < 4; fn++){
      const int krow = fn * 16 + lr;
#pragma unroll
      for (int kh = 0; kh < 2; kh++){
        const int chunk = (kh * 4 + lg) ^ rsw;
        s16x8 kf = *(const s16x8*)&Kl[cur][krow * 64 + chunk * 8];
        sv[0][fn] = __builtin_amdgcn_mfma_f32_16x16x32_bf16(aq[0][kh], kf, sv[0][fn], 0, 0, 0);
        sv[1][fn] = __builtin_amdgcn_mfma_f32_16x16x32_bf16(aq[1][kh], kf, sv[1][fn], 0, 0, 0);
      }
    }

#pragma unroll
    for (int rb = 0; rb < 2; rb++){
      float p[4][4];
#pragma unroll
      for (int i = 0; i < 4; i++){
        float s0 = sv[rb][0][i], s1 = sv[rb][1][i];
        float s2 = sv[rb][2][i], s3 = sv[rb][3][i];
        float rmax = fmaxf(fmaxf(s0, s1), fmaxf(s2, s3));
#pragma unroll
        for (int mm = 8; mm > 0; mm >>= 1) rmax = fmaxf(rmax, __shfl_xor(rmax, mm));
        if (__any(rmax > m_i[rb][i] + 8.0f)){       // wave-uniform rescale (rare)
          float mnew = fmaxf(m_i[rb][i], rmax);
          float fac = __expf(m_i[rb][i] - mnew);
          l_i[rb][i] *= fac;
#pragma unroll
          for (int fn = 0; fn < 4; fn++) ao[rb][fn][i] *= fac;
          m_i[rb][i] = mnew;
        }
        const float m = m_i[rb][i];
        float p0 = __expf(s0 - m), p1 = __expf(s1 - m);
        float p2 = __expf(s2 - m), p3 = __expf(s3 - m);
        p[0][i] = p0; p[1][i] = p1; p[2][i] = p2; p[3][i] = p3;
        l_i[rb][i] += (p0 + p1) + (p2 + p3);        // per-lane partial sum
      }
#pragma unroll
      for (int fn = 0; fn < 4; fn++)
#pragma unroll
        for (int i = 0; i < 4; i++)
          Pl[w][rb * 16 + lg * 4 + i][fn * 16 + lr] = f2bf(p[fn][i]);
    }

    s16x8 vf[4][2];
#pragma unroll
    for (int fn = 0; fn < 4; fn++){
      const int vrow = fn * 16 + lr;
#pragma unroll
      for (int kh = 0; kh < 2; kh++){
        const int chunk = (kh * 4 + lg) ^ rsw;
        vf[fn][kh] = *(const s16x8*)&Vl[cur][vrow * 64 + chunk * 8];
      }
    }
#pragma unroll
    for (int rb = 0; rb < 2; rb++){
      s16x8 pa0 = *(const s16x8*)&Pl[w][rb * 16 + lr][lg * 8];
      s16x8 pa1 = *(const s16x8*)&Pl[w][rb * 16 + lr][32 + lg * 8];
#pragma unroll
      for (int fn = 0; fn < 4; fn++){
        ao[rb][fn] = __builtin_amdgcn_mfma_f32_16x16x32_bf16(pa0, vf[fn][0], ao[rb][fn], 0, 0, 0);
        ao[rb][fn] = __builtin_amdgcn_mfma_f32_16x16x32_bf16(pa1, vf[fn][1], ao[rb][fn], 0, 0, 0);
      }
    }
  }

  // final cross-lane sum of the per-lane l partials (16 lr lanes per row)
#pragma unroll
  for (int rb = 0; rb < 2; rb++)
#pragma unroll
    for (int i = 0; i < 4; i++)
#pragma unroll
      for (int mm = 8; mm > 0; mm >>= 1) l_i[rb][i] += __shfl_xor(l_i[rb][i], mm);

#pragma unroll
  for (int rb = 0; rb < 2; rb++)
#pragma unroll
    for (int fn = 0; fn < 4; fn++)
#pragma unroll
      for (int i = 0; i < 4; i++){
        float v = ao[rb][fn][i] / l_i[rb][i];
        attnC[(size_t)(b * NSEQ + q0 + rb * 16 + lg * 4 + i) * D_EMB + h * HS + fn * 16 + lr] = f2bf(v);
      }
}

// ---------------- host ----------------
extern "C" void kernel_launch(void* const* d_in, const int* in_sizes, int n_in,
                              void* d_out, int out_size, void* d_ws, size_t ws_size,
                              hipStream_t stream)
{
  const float* x    = (const float*)d_in[0];
  const float* Wq   = (const float*)d_in[1];
  const float* bq   = (const float*)d_in[2];
  const float* Wk   = (const float*)d_in[3];
  const float* bk   = (const float*)d_in[4];
  const float* Wv   = (const float*)d_in[5];
  const float* bv   = (const float*)d_in[6];
  const float* Wp   = (const float*)d_in[7];
  const float* bp   = (const float*)d_in[8];
  const float* W1   = (const float*)d_in[9];
  const float* b1   = (const float*)d_in[10];
  const float* W2   = (const float*)d_in[11];
  const float* b2   = (const float*)d_in[12];
  const float* ln1g = (const float*)d_in[13];
  const float* ln1b = (const float*)d_in[14];
  const float* ln2g = (const float*)d_in[15];
  const float* ln2b = (const float*)d_in[16];
  float* out = (float*)d_out;

  char* ws = (char*)d_ws;
  size_t off = 0;
  auto mk = [&](size_t bytes)->void*{ void* p = ws + off; off += (bytes + 255) & ~(size_t)255; return p; };
  u16*  h1    = (u16*) mk((size_t)MTOT * D_EMB * 2);
  u16*  Qb    = (u16*) mk((size_t)MTOT * D_EMB * 2);
  u16*  Kb    = (u16*) mk((size_t)MTOT * D_EMB * 2);
  u16*  VTb   = (u16*) mk((size_t)MTOT * D_EMB * 2);
  u16*  attnC = (u16*) mk((size_t)MTOT * D_EMB * 2);
  float* x1   = (float*)mk((size_t)MTOT * D_EMB * 4);
  u16*  h2    = (u16*) mk((size_t)MTOT * D_EMB * 2);
  u16*  ffb   = (u16*) mk((size_t)MTOT * DFF * 2);
  u16*  WqkvT = (u16*) mk((size_t)3 * D_EMB * D_EMB * 2);
  u16*  WpT   = (u16*) mk((size_t)D_EMB * D_EMB * 2);
  u16*  W1T   = (u16*) mk((size_t)D_EMB * DFF * 2);
  u16*  W2T   = (u16*) mk((size_t)D_EMB * DFF * 2);

  dim3 tb(32, 8, 1);
  transpose_cvt<<<dim3(HS/32, D_EMB/32, NH), tb, 0, stream>>>(Wq, WqkvT,                         D_EMB, HS, (size_t)D_EMB*HS, (size_t)HS*D_EMB);
  transpose_cvt<<<dim3(HS/32, D_EMB/32, NH), tb, 0, stream>>>(Wk, WqkvT + (size_t)D_EMB*D_EMB,   D_EMB, HS, (size_t)D_EMB*HS, (size_t)HS*D_EMB);
  transpose_cvt<<<dim3(HS/32, D_EMB/32, NH), tb, 0, stream>>>(Wv, WqkvT + (size_t)2*D_EMB*D_EMB, D_EMB, HS, (size_t)D_EMB*HS, (size_t)HS*D_EMB);
  transpose_cvt<<<dim3(D_EMB/32, D_EMB/32, 1), tb, 0, stream>>>(Wp, WpT,  D_EMB, D_EMB, 0, 0);
  transpose_cvt<<<dim3(DFF/32,  D_EMB/32, 1), tb, 0, stream>>>(W1, W1T,  D_EMB, DFF,   0, 0);
  transpose_cvt<<<dim3(D_EMB/32, DFF/32,  1), tb, 0, stream>>>(W2, W2T,  DFF,   D_EMB, 0, 0);

  ln_kernel<<<MTOT, 256, 0, stream>>>(x, ln1g, ln1b, h1);

  // QKV: M=8192, N=3072, K=1024 — 128x256, 512 thr, grid 64x12=768
  gemm2ph<0,128,256,512><<<dim3(MTOT/128, 3*D_EMB/256), 512, 0, stream>>>(
      h1, WqkvT, MTOT, 3*D_EMB, D_EMB, bq, bk, bv, nullptr, Qb, Kb, VTb);

  attn_kernel<<<NB*NH*(NSEQ/128), 256, 0, stream>>>(Qb, Kb, VTb, attnC);

  // proj: M=8192, N=1024, K=1024 — 64x128 blocks (wave tile 32x64),
  // grid 128x8=1024 -> 4 blocks/CU (round-12 TLP fix)
  gemm2ph<1,64,128,256><<<dim3(MTOT/64, D_EMB/128), 256, 0, stream>>>(
      attnC, WpT, MTOT, D_EMB, D_EMB, bp, nullptr, nullptr, x, x1, nullptr, nullptr);

  ln_kernel<<<MTOT, 256, 0, stream>>>(x1, ln2g, ln2b, h2);

  // FF1: M=8192, N=4096, K=1024 — 128x256, grid 64x16=1024
  gemm2ph<2,128,256,512><<<dim3(MTOT/128, DFF/256), 512, 0, stream>>>(
      h2, W1T, MTOT, DFF, D_EMB, b1, nullptr, nullptr, nullptr, ffb, nullptr, nullptr);

  // FF2: M=8192, N=1024, K=4096 — 64x128 blocks, grid 128x8=1024
  gemm2ph<1,64,128,256><<<dim3(MTOT/64, D_EMB/128), 256, 0, stream>>>(
      ffb, W2T, MTOT, D_EMB, DFF, b2, nullptr, nullptr, x1, out, nullptr, nullptr);
}

// Round 13
// 434.431 us; speedup vs baseline: 1.1622x; 1.0399x over previous
//
#include <hip/hip_runtime.h>
#include <cstdint>
#include <cstddef>

typedef unsigned short u16;
typedef __attribute__((ext_vector_type(4))) float f32x4;
typedef __attribute__((ext_vector_type(8))) short s16x8;

#define D_EMB 1024
#define NSEQ 1024
#define NB 8
#define NH 16
#define HS 64
#define DFF 4096
#define MTOT (NB*NSEQ)

__device__ __forceinline__ u16 f2bf(float f){
  unsigned u = __float_as_uint(f);
  u += 0x7FFFu + ((u >> 16) & 1u);     // round-to-nearest-even
  return (u16)(u >> 16);
}
// truncating convert (P-tile only: P>0, <=1 ULP bias cancels in softmax ratio)
__device__ __forceinline__ u16 bft(float f){ return (u16)(__float_as_uint(f) >> 16); }

__device__ __forceinline__ void gload_lds16(const void* g, void* l){
  __builtin_amdgcn_global_load_lds((const __attribute__((address_space(1))) void*)g,
                                   (__attribute__((address_space(3))) void*)l, 16, 0, 0);
}

// ---------------- tiled transpose + fp32->bf16 convert ----------------
__global__ void transpose_cvt(const float* __restrict__ in, u16* __restrict__ out,
                              int R, int C, size_t inStride, size_t outStride){
  __shared__ float t[32][33];
  const float* ip = in + (size_t)blockIdx.z * inStride;
  u16* op = out + (size_t)blockIdx.z * outStride;
  int c0 = blockIdx.x * 32, r0 = blockIdx.y * 32;
  int tx = threadIdx.x, ty = threadIdx.y;
#pragma unroll
  for (int j = 0; j < 32; j += 8)
    t[ty + j][tx] = ip[(size_t)(r0 + ty + j) * C + (c0 + tx)];
  __syncthreads();
#pragma unroll
  for (int j = 0; j < 32; j += 8)
    op[(size_t)(c0 + ty + j) * R + (r0 + tx)] = f2bf(t[tx][ty + j]);
}

// ---------------- LayerNorm (fp32 in, bf16 out) ----------------
__global__ __launch_bounds__(256) void ln_kernel(const float* __restrict__ x,
    const float* __restrict__ g, const float* __restrict__ bb, u16* __restrict__ out){
  int row = blockIdx.x;
  const float* xr = x + (size_t)row * D_EMB;
  int c = threadIdx.x * 4;
  f32x4 v = *(const f32x4*)(xr + c);
  float s1 = v[0] + v[1] + v[2] + v[3];
  float s2 = v[0]*v[0] + v[1]*v[1] + v[2]*v[2] + v[3]*v[3];
#pragma unroll
  for (int m = 32; m > 0; m >>= 1){ s1 += __shfl_xor(s1, m); s2 += __shfl_xor(s2, m); }
  __shared__ float ps1[4], ps2[4];
  int w = threadIdx.x >> 6;
  if ((threadIdx.x & 63) == 0){ ps1[w] = s1; ps2[w] = s2; }
  __syncthreads();
  s1 = ps1[0] + ps1[1] + ps1[2] + ps1[3];
  s2 = ps2[0] + ps2[1] + ps2[2] + ps2[3];
  float mu = s1 * (1.f / D_EMB);
  float var = s2 * (1.f / D_EMB) - mu * mu;
  float rs = rsqrtf(var + 1e-5f);
  ushort4 o;
  o.x = f2bf((v[0]-mu)*rs*g[c+0] + bb[c+0]);
  o.y = f2bf((v[1]-mu)*rs*g[c+1] + bb[c+1]);
  o.z = f2bf((v[2]-mu)*rs*g[c+2] + bb[c+2]);
  o.w = f2bf((v[3]-mu)*rs*g[c+3] + bb[c+3]);
  *(ushort4*)(out + (size_t)row * D_EMB + c) = o;
}

// ======== 2-phase GEMM template, A-panel-major block order (frozen) ========
// ROUND-13: MODE 0 Q scale = 0.125*log2(e) so attn softmax runs in exp2
// domain (v_exp_f32 is natively 2^x; kills the mul inside every __expf).
template<int MODE, int BMT, int BNT, int NTHR>
__global__ __launch_bounds__(NTHR) void gemm2ph(
    const u16* __restrict__ A, const u16* __restrict__ Bt,
    int M, int N, int K,
    const float* __restrict__ bias0, const float* __restrict__ bias1,
    const float* __restrict__ bias2, const float* __restrict__ resid,
    void* __restrict__ o0, void* __restrict__ o1, void* __restrict__ o2)
{
  constexpr int NWAVE = NTHR/64;
  constexpr int WCN = BNT/64, WRN = NWAVE/WCN;
  constexpr int WROWS = BMT/WRN;                 // rows per wave
  constexpr int RF = WROWS/16;                   // row fragments per wave
  static_assert(RF*16*WRN == BMT, "wave tiling must cover BMT");
  constexpr int RPP = NTHR/4;                    // rows staged per pass
  constexpr int ALD = (BMT*32)/(NTHR*8);         // 16B loads/thread for A
  constexpr int BLD = (BNT*32)/(NTHR*8);
  __shared__ alignas(16) u16 Al[2][BMT*32];
  __shared__ alignas(16) u16 Bl[2][BNT*32];

  const int tid = threadIdx.x;
  const int wid = tid>>6, lane = tid&63, lr = lane&15, lg = lane>>4;
  const int wr = wid/WCN, wc = wid%WCN;

  // XCD swizzle (all grids divisible by 8) + A-panel-major (n inner)
  const int gx = gridDim.x;
  const int gy = gridDim.y;
  const int nwg = gx * gy;
  const int bid = blockIdx.x + blockIdx.y*gx;
  const int wg = (bid&7)*(nwg>>3) + (bid>>3);
  const int m0 = (wg / gy) * BMT;    // consecutive wg share m0 (A panel)
  const int n0 = (wg % gy) * BNT;

  const int srow = tid>>2;                                   // staging row
  const int scs = (((tid&3) - ((srow>>1)&3)) & 3) * 8;       // inv-swizzled src chunk

  auto stage = [&](int buf, int kt){
    const u16* asrc = A + (size_t)(m0 + srow)*K + kt*32 + scs;
#pragma unroll
    for (int r = 0; r < ALD; ++r)
      gload_lds16(asrc + (size_t)(r*RPP)*K, &Al[buf][r*(NTHR*8) + tid*8]);
    const u16* bsrc = Bt + (size_t)(n0 + srow)*K + kt*32 + scs;
#pragma unroll
    for (int r = 0; r < BLD; ++r)
      gload_lds16(bsrc + (size_t)(r*RPP)*K, &Bl[buf][r*(NTHR*8) + tid*8]);
  };

  f32x4 acc[RF][4];
#pragma unroll
  for (int i = 0; i < RF; i++)
#pragma unroll
    for (int j = 0; j < 4; j++) acc[i][j] = {0.f,0.f,0.f,0.f};

  const int nk = K/32;
  stage(0, 0);
  for (int kt = 0; kt < nk; ++kt){
    __syncthreads();                   // drains vmcnt: stage(kt) visible
    if (kt + 1 < nk) stage((kt+1)&1, kt+1);
    const int buf = kt & 1;
    s16x8 af[RF], bf[4];
#pragma unroll
    for (int i = 0; i < RF; i++){
      const int ar = wr*WROWS + i*16 + lr;
      af[i] = *(const s16x8*)&Al[buf][ar*32 + (((lg + (ar>>1)) & 3)<<3)];
    }
#pragma unroll
    for (int j = 0; j < 4; j++){
      const int br = wc*64 + j*16 + lr;
      bf[j] = *(const s16x8*)&Bl[buf][br*32 + (((lg + (br>>1)) & 3)<<3)];
    }
#pragma unroll
    for (int i = 0; i < RF; i++)
#pragma unroll
      for (int j = 0; j < 4; j++)
        acc[i][j] = __builtin_amdgcn_mfma_f32_16x16x32_bf16(af[i], bf[j], acc[i][j], 0, 0, 0);
  }

  // epilogue: lane holds C[row=lg*4+i][col=lr] per 16x16 fragment
#pragma unroll
  for (int fm = 0; fm < RF; fm++){
    const int gmb = m0 + wr*WROWS + fm*16 + lg*4;
#pragma unroll
    for (int fn = 0; fn < 4; fn++){
      const int gn = n0 + wc*64 + fn*16 + lr;
#pragma unroll
      for (int i = 0; i < 4; i++){
        const int gm = gmb + i;
        float v = acc[fm][fn][i];
        if (MODE == 0){
          const int cls = gn >> 10, nn = gn & 1023;
          if (cls == 0)      ((u16*)o0)[(size_t)gm * D_EMB + nn] = f2bf((v + bias0[nn]) * 0.18033688f); // 0.125*log2e
          else if (cls == 1) ((u16*)o1)[(size_t)gm * D_EMB + nn] = f2bf(v + bias1[nn]);
          else {
            const int hh = nn >> 6, ss = nn & 63, bb = gm >> 10, tt = gm & 1023;
            ((u16*)o2)[(((size_t)(bb * NH + hh)) * HS + ss) * NSEQ + tt] = f2bf(v + bias2[nn]);
          }
        } else if (MODE == 1){
          ((float*)o0)[(size_t)gm * N + gn] = resid[(size_t)gm * N + gn] + v + bias0[gn];
        } else {
          float y = v + bias0[gn];
          y = y > 0.f ? y : 0.01f * y;
          ((u16*)o0)[(size_t)gm * N + gn] = f2bf(y);
        }
      }
    }
  }
}

// ---------------- flash attention (round-13: exp2 + gated reduce) ----------------
// Scores arrive pre-scaled by 0.125*log2e -> softmax in exp2 domain (exact
// after normalization). Cross-lane max reduce runs ONLY inside the rare
// defer-max branch (__any on per-lane max keeps it wave-uniform; m stays
// row-consistent because it is updated only with the fully-reduced value).
// P bounded by 2^8. l_i per-lane partial, reduced once at the end.
__global__ __launch_bounds__(256) void attn_kernel(
    const u16* __restrict__ Qb, const u16* __restrict__ Kb, const u16* __restrict__ VT,
    u16* __restrict__ attnC)
{
  const int bid = blockIdx.x;
  const int bh = bid & 127, qt = bid >> 7;
  const int b = bh >> 4, h = bh & 15;
  const int tid = threadIdx.x, w = tid >> 6, lane = tid & 63;
  const int lr = lane & 15, lg = lane >> 4;
  const int q0 = qt * 128 + w * 32;

  __shared__ alignas(16) u16 Kl[2][64*64];
  __shared__ alignas(16) u16 Vl[2][64*64];
  __shared__ alignas(16) u16 Pl[4][32][72];

  const int srow = tid >> 3, scg = tid & 7;
  const u16* kbase = Kb + (size_t)(b * NSEQ) * D_EMB + h * HS;
  const u16* vbase = VT + ((size_t)(b * NH + h)) * HS * NSEQ;

  auto stage = [&](int buf, int kt){
    const int tk = kt * 64;
#pragma unroll
    for (int p = 0; p < 2; ++p){
      const int row = srow + p * 32;
      const int sc = scg ^ (row & 7);
      gload_lds16(kbase + (size_t)(tk + row) * D_EMB + sc * 8, &Kl[buf][(p * 256 + tid) * 8]);
      gload_lds16(vbase + (size_t)row * NSEQ + tk + sc * 8,    &Vl[buf][(p * 256 + tid) * 8]);
    }
  };

  s16x8 aq[2][2];
#pragma unroll
  for (int rb = 0; rb < 2; rb++)
#pragma unroll
    for (int kh = 0; kh < 2; kh++)
      aq[rb][kh] = *(const s16x8*)(Qb + (size_t)(b * NSEQ + q0 + rb * 16 + lr) * D_EMB
                                   + h * HS + kh * 32 + lg * 8);

  float m_i[2][4], l_i[2][4];
  f32x4 zero = {0.f, 0.f, 0.f, 0.f};
  f32x4 ao[2][4];
#pragma unroll
  for (int rb = 0; rb < 2; rb++)
#pragma unroll
    for (int i = 0; i < 4; i++){ m_i[rb][i] = -1e30f; l_i[rb][i] = 0.f; ao[rb][i] = zero; }

  const int rsw = lr & 7;

  stage(0, 0);
  for (int kt = 0; kt < NSEQ / 64; ++kt){
    __syncthreads();
    if (kt + 1 < NSEQ / 64) stage((kt + 1) & 1, kt + 1);
    const int cur = kt & 1;

    f32x4 sv[2][4];
#pragma unroll
    for (int rb = 0; rb < 2; rb++)
#pragma unroll
      for (int fn = 0; fn < 4; fn++) sv[rb][fn] = zero;
#pragma unroll
    for (int fn = 0; fn < 4; fn++){
      const int krow = fn * 16 + lr;
#pragma unroll
      for (int kh = 0; kh < 2; kh++){
        const int chunk = (kh * 4 + lg) ^ rsw;
        s16x8 kf = *(const s16x8*)&Kl[cur][krow * 64 + chunk * 8];
        sv[0][fn] = __builtin_amdgcn_mfma_f32_16x16x32_bf16(aq[0][kh], kf, sv[0][fn], 0, 0, 0);
        sv[1][fn] = __builtin_amdgcn_mfma_f32_16x16x32_bf16(aq[1][kh], kf, sv[1][fn], 0, 0, 0);
      }
    }

#pragma unroll
    for (int rb = 0; rb < 2; rb++){
      float p[4][4];
#pragma unroll
      for (int i = 0; i < 4; i++){
        float s0 = sv[rb][0][i], s1 = sv[rb][1][i];
        float s2 = sv[rb][2][i], s3 = sv[rb][3][i];
        float lmax = fmaxf(fmaxf(s0, s1), fmaxf(s2, s3));     // per-lane only
        if (__any(lmax > m_i[rb][i] + 8.0f)){                 // rare, wave-uniform
          float rmax = lmax;
#pragma unroll
          for (int mm = 8; mm > 0; mm >>= 1) rmax = fmaxf(rmax, __shfl_xor(rmax, mm));
          float mnew = fmaxf(m_i[rb][i], rmax);
          float fac = exp2f(m_i[rb][i] - mnew);
          l_i[rb][i] *= fac;
#pragma unroll
          for (int fn = 0; fn < 4; fn++) ao[rb][fn][i] *= fac;
          m_i[rb][i] = mnew;
        }
        const float m = m_i[rb][i];
        float p0 = exp2f(s0 - m), p1 = exp2f(s1 - m);
        float p2 = exp2f(s2 - m), p3 = exp2f(s3 - m);
        p[0][i] = p0; p[1][i] = p1; p[2][i] = p2; p[3][i] = p3;
        l_i[rb][i] += (p0 + p1) + (p2 + p3);        // per-lane partial sum
      }
#pragma unroll
      for (int fn = 0; fn < 4; fn++)
#pragma unroll
        for (int i = 0; i < 4; i++)
          Pl[w][rb * 16 + lg * 4 + i][fn * 16 + lr] = bft(p[fn][i]);
    }

    s16x8 vf[4][2];
#pragma unroll
    for (int fn = 0; fn < 4; fn++){
      const int vrow = fn * 16 + lr;
#pragma unroll
      for (int kh = 0; kh < 2; kh++){
        const int chunk = (kh * 4 + lg) ^ rsw;
        vf[fn][kh] = *(const s16x8*)&Vl[cur][vrow * 64 + chunk * 8];
      }
    }
#pragma unroll
    for (int rb = 0; rb < 2; rb++){
      s16x8 pa0 = *(const s16x8*)&Pl[w][rb * 16 + lr][lg * 8];
      s16x8 pa1 = *(const s16x8*)&Pl[w][rb * 16 + lr][32 + lg * 8];
#pragma unroll
      for (int fn = 0; fn < 4; fn++){
        ao[rb][fn] = __builtin_amdgcn_mfma_f32_16x16x32_bf16(pa0, vf[fn][0], ao[rb][fn], 0, 0, 0);
        ao[rb][fn] = __builtin_amdgcn_mfma_f32_16x16x32_bf16(pa1, vf[fn][1], ao[rb][fn], 0, 0, 0);
      }
    }
  }

  // final cross-lane sum of the per-lane l partials (16 lr lanes per row)
#pragma unroll
  for (int rb = 0; rb < 2; rb++)
#pragma unroll
    for (int i = 0; i < 4; i++)
#pragma unroll
      for (int mm = 8; mm > 0; mm >>= 1) l_i[rb][i] += __shfl_xor(l_i[rb][i], mm);

#pragma unroll
  for (int rb = 0; rb < 2; rb++)
#pragma unroll
    for (int fn = 0; fn < 4; fn++)
#pragma unroll
      for (int i = 0; i < 4; i++){
        float v = ao[rb][fn][i] / l_i[rb][i];
        attnC[(size_t)(b * NSEQ + q0 + rb * 16 + lg * 4 + i) * D_EMB + h * HS + fn * 16 + lr] = f2bf(v);
      }
}

// ---------------- host ----------------
extern "C" void kernel_launch(void* const* d_in, const int* in_sizes, int n_in,
                              void* d_out, int out_size, void* d_ws, size_t ws_size,
                              hipStream_t stream)
{
  const float* x    = (const float*)d_in[0];
  const float* Wq   = (const float*)d_in[1];
  const float* bq   = (const float*)d_in[2];
  const float* Wk   = (const float*)d_in[3];
  const float* bk   = (const float*)d_in[4];
  const float* Wv   = (const float*)d_in[5];
  const float* bv   = (const float*)d_in[6];
  const float* Wp   = (const float*)d_in[7];
  const float* bp   = (const float*)d_in[8];
  const float* W1   = (const float*)d_in[9];
  const float* b1   = (const float*)d_in[10];
  const float* W2   = (const float*)d_in[11];
  const float* b2   = (const float*)d_in[12];
  const float* ln1g = (const float*)d_in[13];
  const float* ln1b = (const float*)d_in[14];
  const float* ln2g = (const float*)d_in[15];
  const float* ln2b = (const float*)d_in[16];
  float* out = (float*)d_out;

  char* ws = (char*)d_ws;
  size_t off = 0;
  auto mk = [&](size_t bytes)->void*{ void* p = ws + off; off += (bytes + 255) & ~(size_t)255; return p; };
  u16*  h1    = (u16*) mk((size_t)MTOT * D_EMB * 2);
  u16*  Qb    = (u16*) mk((size_t)MTOT * D_EMB * 2);
  u16*  Kb    = (u16*) mk((size_t)MTOT * D_EMB * 2);
  u16*  VTb   = (u16*) mk((size_t)MTOT * D_EMB * 2);
  u16*  attnC = (u16*) mk((size_t)MTOT * D_EMB * 2);
  float* x1   = (float*)mk((size_t)MTOT * D_EMB * 4);
  u16*  h2    = (u16*) mk((size_t)MTOT * D_EMB * 2);
  u16*  ffb   = (u16*) mk((size_t)MTOT * DFF * 2);
  u16*  WqkvT = (u16*) mk((size_t)3 * D_EMB * D_EMB * 2);
  u16*  WpT   = (u16*) mk((size_t)D_EMB * D_EMB * 2);
  u16*  W1T   = (u16*) mk((size_t)D_EMB * DFF * 2);
  u16*  W2T   = (u16*) mk((size_t)D_EMB * DFF * 2);

  dim3 tb(32, 8, 1);
  transpose_cvt<<<dim3(HS/32, D_EMB/32, NH), tb, 0, stream>>>(Wq, WqkvT,                         D_EMB, HS, (size_t)D_EMB*HS, (size_t)HS*D_EMB);
  transpose_cvt<<<dim3(HS/32, D_EMB/32, NH), tb, 0, stream>>>(Wk, WqkvT + (size_t)D_EMB*D_EMB,   D_EMB, HS, (size_t)D_EMB*HS, (size_t)HS*D_EMB);
  transpose_cvt<<<dim3(HS/32, D_EMB/32, NH), tb, 0, stream>>>(Wv, WqkvT + (size_t)2*D_EMB*D_EMB, D_EMB, HS, (size_t)D_EMB*HS, (size_t)HS*D_EMB);
  transpose_cvt<<<dim3(D_EMB/32, D_EMB/32, 1), tb, 0, stream>>>(Wp, WpT,  D_EMB, D_EMB, 0, 0);
  transpose_cvt<<<dim3(DFF/32,  D_EMB/32, 1), tb, 0, stream>>>(W1, W1T,  D_EMB, DFF,   0, 0);
  transpose_cvt<<<dim3(D_EMB/32, DFF/32,  1), tb, 0, stream>>>(W2, W2T,  DFF,   D_EMB, 0, 0);

  ln_kernel<<<MTOT, 256, 0, stream>>>(x, ln1g, ln1b, h1);

  // QKV: M=8192, N=3072, K=1024 — 128x256, 512 thr, grid 64x12=768
  gemm2ph<0,128,256,512><<<dim3(MTOT/128, 3*D_EMB/256), 512, 0, stream>>>(
      h1, WqkvT, MTOT, 3*D_EMB, D_EMB, bq, bk, bv, nullptr, Qb, Kb, VTb);

  attn_kernel<<<NB*NH*(NSEQ/128), 256, 0, stream>>>(Qb, Kb, VTb, attnC);

  // proj: M=8192, N=1024, K=1024 — 64x128 blocks, grid 128x8=1024
  gemm2ph<1,64,128,256><<<dim3(MTOT/64, D_EMB/128), 256, 0, stream>>>(
      attnC, WpT, MTOT, D_EMB, D_EMB, bp, nullptr, nullptr, x, x1, nullptr, nullptr);

  ln_kernel<<<MTOT, 256, 0, stream>>>(x1, ln2g, ln2b, h2);

  // FF1: M=8192, N=4096, K=1024 — 128x256, grid 64x16=1024
  gemm2ph<2,128,256,512><<<dim3(MTOT/128, DFF/256), 512, 0, stream>>>(
      h2, W1T, MTOT, DFF, D_EMB, b1, nullptr, nullptr, nullptr, ffb, nullptr, nullptr);

  // FF2: M=8192, N=1024, K=4096 — 64x128 blocks, grid 128x8=1024
  gemm2ph<1,64,128,256><<<dim3(MTOT/64, D_EMB/128), 256, 0, stream>>>(
      ffb, W2T, MTOT, D_EMB, DFF, b2, nullptr, nullptr, x1, out, nullptr, nullptr);
}